// Round 8
// baseline (1595.039 us; speedup 1.0000x reference)
//
#include <hip/hip_runtime.h>

#define NN 50000
#define NE 800000
#define H 256
#define NB 12500            // edge blocks (64 edges each)
#define NBINS 50176         // NN padded
#define HBLK 782            // node blocks (64 nodes each)

typedef __bf16 bf16x8 __attribute__((ext_vector_type(8)));
typedef __bf16 bf16x4 __attribute__((ext_vector_type(4)));
typedef float f32x4 __attribute__((ext_vector_type(4)));

static __device__ __forceinline__ f32x4 mfma16(bf16x8 a, bf16x8 b, f32x4 c) {
  return __builtin_amdgcn_mfma_f32_16x16x32_bf16(a, b, c, 0, 0, 0);
}
static __device__ __forceinline__ bf16x8 bzero8() {
  bf16x8 z;
#pragma unroll
  for (int j = 0; j < 8; ++j) z[j] = (__bf16)0.f;
  return z;
}
static __device__ __forceinline__ float silu_f(float v) {
  return v * __builtin_amdgcn_rcpf(1.f + __builtin_amdgcn_exp2f(v * -1.442695041f));
}
// Fragment-layout row base for buffers PS/PD/h:
// addr(n,c) = rbase(n) + coff(c), coff(c) = (c>>6)<<12 | ((c>>4)&3)<<8 | (c&15)
static __device__ __forceinline__ int rbase(int n) {
  return ((n >> 6) << 14) + (((n >> 4) & 3) << 10) + ((n & 3) << 6) + (((n >> 2) & 3) << 4);
}

// ---------------------------------------------------------------------------
// prep (blocks 0..4674) + hist (blocks 4675..7799).
// Repack fp32->bf16 [chunk][n][32k]:
//   wsd [3][8][512][32] (Ws|Wd of e1w rows 0..511)
//   e2p/n2p [3][8][256][32], n1p [3][16][256][32], outp [8][64][32]
// Tables (bf16, [n][32k] B-layout, k = role*3+col 0..23, rest 0):
//   TNp/TSp/TDp [3][256][32]; TDp includes e1b, TNp includes n1b. TR fp32.
// cnt must be zeroed before this kernel (hist atomics).
// ---------------------------------------------------------------------------
__global__ void preph_kernel(
    const float* __restrict__ e1w, const float* __restrict__ e2w,
    const float* __restrict__ n1w, const float* __restrict__ n2w,
    const float* __restrict__ outw, const float* __restrict__ e1b,
    const float* __restrict__ n1b,
    const float* __restrict__ rel_embs, const float* __restrict__ role_embs,
    const float* __restrict__ col_embs, const int* __restrict__ dstI,
    __bf16* __restrict__ wsd, __bf16* __restrict__ e2p,
    __bf16* __restrict__ n1p, __bf16* __restrict__ n2p,
    __bf16* __restrict__ outp, int* __restrict__ cnt,
    float* __restrict__ TR, __bf16* __restrict__ TNp,
    __bf16* __restrict__ TSp, __bf16* __restrict__ TDp)
{
  if (blockIdx.x >= 4675) {
    const int e = (blockIdx.x - 4675) * 256 + threadIdx.x;
    if (e < NE) atomicAdd(&cnt[dstI[e]], 1);
    return;
  }
  int i = blockIdx.x * 256 + threadIdx.x;
  if (i < 3 * 131072) {
    const int l = i / 131072, rem = i % 131072;
    const int c = rem >> 14, r2 = rem & 16383;
    const int n = r2 >> 5, k = c * 32 + (r2 & 31);
    wsd[i] = (n < 256) ? (__bf16)e1w[((size_t)l * 560 + k) * 256 + n]
                       : (__bf16)e1w[((size_t)l * 560 + 256 + k) * 256 + (n - 256)];
    return;
  }
  i -= 3 * 131072;
  if (i < 3 * 65536) {
    const int l = i / 65536, rem = i % 65536;
    const int c = rem >> 13, r2 = rem & 8191;
    const int n = r2 >> 5, k = c * 32 + (r2 & 31);
    e2p[i] = (__bf16)e2w[((size_t)l * 256 + k) * 256 + n];
    return;
  }
  i -= 3 * 65536;
  if (i < 3 * 131072) {
    const int l = i / 131072, rem = i % 131072;
    const int c = rem >> 13, r2 = rem & 8191;
    const int n = r2 >> 5, k = c * 32 + (r2 & 31);   // k < 512
    n1p[i] = (__bf16)n1w[((size_t)l * 528 + k) * 256 + n];
    return;
  }
  i -= 3 * 131072;
  if (i < 3 * 65536) {
    const int l = i / 65536, rem = i % 65536;
    const int c = rem >> 13, r2 = rem & 8191;
    const int n = r2 >> 5, k = c * 32 + (r2 & 31);
    n2p[i] = (__bf16)n2w[((size_t)l * 256 + k) * 256 + n];
    return;
  }
  i -= 3 * 65536;
  if (i < 16384) {
    const int c = i >> 11, r2 = i & 2047;
    const int n = r2 >> 5, k = c * 32 + (r2 & 31);
    outp[i] = (__bf16)outw[(size_t)k * 64 + n];
    return;
  }
  i -= 16384;
  if (i < 768) {
    const int l = i >> 8, c = i & 255;
    float w[48];
#pragma unroll
    for (int j = 0; j < 48; ++j) w[j] = e1w[((size_t)l * 560 + 512 + j) * 256 + c];
#pragma unroll
    for (int r = 0; r < 8; ++r) {
      float s = 0.f;
#pragma unroll
      for (int j = 0; j < 16; ++j) s += rel_embs[l * 128 + r * 16 + j] * w[j];
      TR[((size_t)l * 8 + r) * 256 + c] = s;
    }
    float wn[16];
#pragma unroll
    for (int j = 0; j < 16; ++j) wn[j] = n1w[((size_t)l * 528 + 512 + j) * 256 + c];
    const float bias = e1b[l * 256 + c];
    const float nbias = n1b[l * 256 + c];
    const size_t ob = ((size_t)l * 256 + c) * 32;
#pragma unroll
    for (int ro = 0; ro < 8; ++ro) {
      float ss = 0.f, sd = 0.f, sn = 0.f;
#pragma unroll
      for (int j = 0; j < 8; ++j) {
        const float re = role_embs[l * 64 + ro * 8 + j];
        ss += re * w[16 + j];
        sd += re * w[24 + j];
        sn += re * wn[j];
      }
#pragma unroll
      for (int co = 0; co < 3; ++co) {
        float cs = 0.f, cd = 0.f, cn = 0.f;
#pragma unroll
        for (int j = 0; j < 8; ++j) {
          const float ce = col_embs[l * 24 + co * 8 + j];
          cs += ce * w[32 + j];
          cd += ce * w[40 + j];
          cn += ce * wn[8 + j];
        }
        const int k = ro * 3 + co;
        TSp[ob + k] = (__bf16)(ss + cs);
        TDp[ob + k] = (__bf16)(sd + cd + bias);
        TNp[ob + k] = (__bf16)(sn + cn + nbias);
      }
    }
#pragma unroll
    for (int k = 24; k < 32; ++k) {
      TSp[ob + k] = (__bf16)0.f;
      TDp[ob + k] = (__bf16)0.f;
      TNp[ob + k] = (__bf16)0.f;
    }
  }
}

// ---------------------------------------------------------------------------
// Scan: cnt -> exclusive prefix (in place, mutable for scatter) + stable cnt2.
// ---------------------------------------------------------------------------
__global__ __launch_bounds__(1024) void scan_kernel(int* __restrict__ cnt,
                                                    int* __restrict__ cnt2) {
  __shared__ int wsum[16];
  __shared__ int carry;
  const int tid = threadIdx.x, lane = tid & 63, wid = tid >> 6;
  if (tid == 0) carry = 0;
  __syncthreads();
  for (int base = 0; base < NBINS; base += 4096) {
    const int idx = base + tid * 4;
    int4 v = make_int4(0, 0, 0, 0);
    if (idx < NBINS) v = *(const int4*)&cnt[idx];
    const int s1 = v.x + v.y, s2 = s1 + v.z, tot = s2 + v.w;
    int x = tot;
#pragma unroll
    for (int d = 1; d < 64; d <<= 1) {
      const int y = __shfl_up(x, d, 64);
      if (lane >= d) x += y;
    }
    if (lane == 63) wsum[wid] = x;
    __syncthreads();
    int wpref = 0;
#pragma unroll
    for (int w = 0; w < 16; ++w)
      if (w < wid) wpref += wsum[w];
    const int ex = carry + wpref + (x - tot);
    if (idx < NBINS) {
      int4 o;
      o.x = ex; o.y = ex + v.x; o.z = ex + s1; o.w = ex + s2;
      *(int4*)&cnt[idx] = o;
      *(int4*)&cnt2[idx] = o;
    }
    __syncthreads();
    if (tid == 0) {
      int s = 0;
#pragma unroll
      for (int w = 0; w < 16; ++w) s += wsum[w];
      carry += s;
    }
    __syncthreads();
  }
}

// ---------------------------------------------------------------------------
// Fused: embed+layer0 PS/PD (blocks 0..781) + scatter perm (782..3906) +
// dstS run-fill (3907..4102). h/PS/PD written in fragment layout (coalesced).
// ---------------------------------------------------------------------------
__global__ __launch_bounds__(256, 3) void scem_kernel(
    const int* __restrict__ dstI, int* __restrict__ cnt,
    const int* __restrict__ cnt2,
    int* __restrict__ perm, int* __restrict__ dstS,
    const float* __restrict__ scalars, const int* __restrict__ ncol,
    const int* __restrict__ nrole,
    const float* __restrict__ colEmb, const float* __restrict__ roleEmb,
    const float* __restrict__ inw, const float* __restrict__ inb,
    const __bf16* __restrict__ wsd,
    const __bf16* __restrict__ TSp, const __bf16* __restrict__ TDp,
    __bf16* __restrict__ h, __bf16* __restrict__ PS, __bf16* __restrict__ PD)
{
  if (blockIdx.x >= 3907) {
    const int n = (blockIdx.x - 3907) * 256 + threadIdx.x;
    if (n < NN) {
      const int st = cnt2[n], en = cnt2[n + 1];
      for (int p = st; p < en; ++p) dstS[p] = n;
    }
    return;
  }
  if (blockIdx.x >= 782) {
    const int e = (blockIdx.x - 782) * 256 + threadIdx.x;
    if (e < NE) {
      const int pos = atomicAdd(&cnt[dstI[e]], 1);
      perm[pos] = e;
    }
    return;
  }
  __shared__ __align__(16) char uni[37888];
  __shared__ int sTi[64];
  auto Ain = (__bf16 (*)[40])uni;    // [64][40] input features (K=32 + pad)
  auto Hs  = (__bf16 (*)[296])uni;   // [64][296] h tile + onehot (aliased)

  const int tid  = threadIdx.x;
  const int lane = tid & 63;
  const int wave = tid >> 6;
  const int l15  = lane & 15;
  const int quad = lane >> 4;
  const int n0   = blockIdx.x * 64;
  const int colW = wave * 64;
  const int fb   = (blockIdx.x << 14) + (wave << 12);   // fragment-store base

  if (tid < 64) {
    const int n = n0 + tid;
    sTi[tid] = (n < NN) ? (nrole[n] * 3 + ncol[n]) : 0;
  }
  {
    const int row = tid >> 2, q = tid & 3;
    const int n = n0 + row;
    __bf16* dp = &Ain[row][q * 8];
    if (n < NN) {
      if (q < 2) {
#pragma unroll
        for (int j = 0; j < 8; ++j) dp[j] = (__bf16)scalars[(size_t)n * 16 + q * 8 + j];
      } else if (q == 2) {
        const int c = ncol[n];
#pragma unroll
        for (int j = 0; j < 8; ++j) dp[j] = (__bf16)colEmb[c * 8 + j];
      } else {
        const int r = nrole[n];
#pragma unroll
        for (int j = 0; j < 8; ++j) dp[j] = (__bf16)roleEmb[r * 8 + j];
      }
    } else {
#pragma unroll
      for (int j = 0; j < 8; ++j) dp[j] = (__bf16)0.f;
    }
  }
  __syncthreads();

  // h-GEMM: single K=32 chunk
  f32x4 acc[4][4] = {};
  {
    bf16x8 bfr[4], afr[4];
#pragma unroll
    for (int nj = 0; nj < 4; ++nj) {
      const int col = colW + nj * 16 + l15;
#pragma unroll
      for (int j = 0; j < 8; ++j) bfr[nj][j] = (__bf16)inw[(quad * 8 + j) * 256 + col];
    }
#pragma unroll
    for (int mi = 0; mi < 4; ++mi)
      afr[mi] = *(const bf16x8*)&Ain[mi * 16 + l15][quad * 8];
#pragma unroll
    for (int mi = 0; mi < 4; ++mi)
#pragma unroll
      for (int nj = 0; nj < 4; ++nj)
        acc[mi][nj] = mfma16(afr[mi], bfr[nj], acc[mi][nj]);
  }
  float bi[4];
#pragma unroll
  for (int nj = 0; nj < 4; ++nj) bi[nj] = inb[colW + nj * 16 + l15];
  __syncthreads();   // Ain reads done before Hs (aliased) write

#pragma unroll
  for (int mi = 0; mi < 4; ++mi)
#pragma unroll
    for (int r = 0; r < 4; ++r) {
      const int row = mi * 16 + quad * 4 + r;
#pragma unroll
      for (int nj = 0; nj < 4; ++nj) {
        const __bf16 hv = (__bf16)(acc[mi][nj][r] + bi[nj]);
        Hs[row][colW + nj * 16 + l15] = hv;
        h[fb + (mi << 10) + ((nj * 4 + r) << 6) + lane] = hv;   // coalesced 128B
      }
    }
  // onehot into Hs cols 256..287
  {
    const int row = tid >> 2, q = tid & 3;
    const int ti = sTi[row];
    bf16x8 v;
#pragma unroll
    for (int j = 0; j < 8; ++j) v[j] = (__bf16)((q * 8 + j == ti) ? 1.f : 0.f);
    *(bf16x8*)&Hs[row][256 + q * 8] = v;
  }
  __syncthreads();

  // P-GEMMs: 8 chunks h @ Wsd + 1 chunk onehot @ TSp/TDp
  for (int hf = 0; hf < 2; ++hf) {
    f32x4 ap[4][4] = {};
#pragma unroll
    for (int c = 0; c < 9; ++c) {
      bf16x8 bfr[4], afr[4];
      const __bf16* bp = (c < 8)
          ? wsd + ((size_t)c * 512 + hf * 256) * 32
          : (hf ? TDp : TSp);
#pragma unroll
      for (int nj = 0; nj < 4; ++nj)
        bfr[nj] = *(const bf16x8*)(bp + ((size_t)(colW + nj * 16 + l15)) * 32 + quad * 8);
#pragma unroll
      for (int mi = 0; mi < 4; ++mi)
        afr[mi] = *(const bf16x8*)&Hs[mi * 16 + l15][c * 32 + quad * 8];
#pragma unroll
      for (int mi = 0; mi < 4; ++mi)
#pragma unroll
        for (int nj = 0; nj < 4; ++nj)
          ap[mi][nj] = mfma16(afr[mi], bfr[nj], ap[mi][nj]);
    }
    __bf16* P = hf ? PD : PS;
#pragma unroll
    for (int mi = 0; mi < 4; ++mi)
#pragma unroll
      for (int nj = 0; nj < 4; ++nj)
#pragma unroll
        for (int r = 0; r < 4; ++r)
          P[fb + (mi << 10) + ((nj * 4 + r) << 6) + lane] = (__bf16)ap[mi][nj][r];
  }
}

// ---------------------------------------------------------------------------
// Fused edge MLP + segmented scatter (sorted by dst, no atomics).
// PS/PD gathered via fragment layout (row base precomputed); agg/bnd bf16.
// ---------------------------------------------------------------------------
__global__ __launch_bounds__(256, 4) void edge_kernel(
    const __bf16* __restrict__ PS, const __bf16* __restrict__ PD,
    __bf16* __restrict__ agg, __bf16* __restrict__ bnd,
    const int* __restrict__ perm, const int* __restrict__ dstS,
    const int* __restrict__ srcI, const int* __restrict__ erel,
    const float* __restrict__ TR,
    const __bf16* __restrict__ e2p, const float* __restrict__ e2b)
{
  __shared__ __align__(16) char uni[34816];
  __shared__ __bf16 sTrel[8][256];
  __shared__ int sSrcB[64], sDstB[64], sDst[64], sRel[64];

  auto A2  = (__bf16 (*)[264])uni;      // [64][264]  m1 row-major
  auto A2t = (__bf16 (*)[68])uni;       // [256][68]  m2 col-major (aliased)

  const int tid  = threadIdx.x;
  const int lane = tid & 63;
  const int wave = tid >> 6;
  const int l15  = lane & 15;
  const int quad = lane >> 4;
  const int e0   = blockIdx.x * 64;
  const int colW = wave * 64;

  if (tid < 64) {
    const int p = perm[e0 + tid];
    const int s = srcI[p];
    sRel[tid] = erel[p];
    const int d = dstS[e0 + tid];
    sDst[tid] = d;
    sSrcB[tid] = rbase(s);
    sDstB[tid] = rbase(d);
  }
  {
    const int r = tid >> 5, cs = (tid & 31) * 8;
    const float* p = TR + r * 256 + cs;
    bf16x8 v;
#pragma unroll
    for (int j = 0; j < 8; ++j) v[j] = (__bf16)p[j];
    *(bf16x8*)&sTrel[r][cs] = v;
  }
  __syncthreads();

  // ---- m1 ----
  {
    const int brow = tid >> 5;
    const int cs = (tid & 31) * 8;
    const int coff = ((cs >> 6) << 12) + (((cs >> 4) & 3) << 8) + (cs & 15);
#pragma unroll
    for (int it = 0; it < 8; ++it) {
      const int row = it * 8 + brow;
      const bf16x8 a = *(const bf16x8*)(PS + sSrcB[row] + coff);
      const bf16x8 b = *(const bf16x8*)(PD + sDstB[row] + coff);
      const bf16x8 t = *(const bf16x8*)&sTrel[sRel[row]][cs];
      bf16x8 o;
#pragma unroll
      for (int j = 0; j < 8; ++j)
        o[j] = (__bf16)silu_f((float)a[j] + (float)b[j] + (float)t[j]);
      *(bf16x8*)&A2[row][cs] = o;
    }
  }
  __syncthreads();

  // ---- GEMM2 ----
  f32x4 acc2[4][4] = {};
#pragma unroll
  for (int c = 0; c < 8; ++c) {
    bf16x8 bfr[4], afr[4];
#pragma unroll
    for (int nj = 0; nj < 4; ++nj)
      bfr[nj] = *(const bf16x8*)(e2p + ((size_t)c * 256 + colW + nj * 16 + l15) * 32 + quad * 8);
#pragma unroll
    for (int mi = 0; mi < 4; ++mi)
      afr[mi] = *(const bf16x8*)&A2[mi * 16 + l15][c * 32 + quad * 8];
#pragma unroll
    for (int mi = 0; mi < 4; ++mi)
#pragma unroll
      for (int nj = 0; nj < 4; ++nj)
        acc2[mi][nj] = mfma16(afr[mi], bfr[nj], acc2[mi][nj]);
  }

  float b2[4];
#pragma unroll
  for (int nj = 0; nj < 4; ++nj) b2[nj] = e2b[colW + nj * 16 + l15];
  __syncthreads();   // A2 reads done before A2t (aliased) write

#pragma unroll
  for (int mi = 0; mi < 4; ++mi)
#pragma unroll
    for (int nj = 0; nj < 4; ++nj) {
      const int col = colW + nj * 16 + l15;
      bf16x4 pv;
#pragma unroll
      for (int r = 0; r < 4; ++r)
        pv[r] = (__bf16)silu_f(acc2[mi][nj][r] + b2[nj]);
      *(bf16x4*)&A2t[col][mi * 16 + quad * 4] = pv;
    }
  __syncthreads();

  // ---- segmented reduce: thread = column; all plain stores (bf16) ----
  {
    const int col = tid;
    const bool f = (lane > 0) && (sDst[lane] != sDst[lane - 1]);
    const unsigned long long mask = __ballot(f);
    bf16x4 v[16];
#pragma unroll
    for (int j = 0; j < 16; ++j) v[j] = *(const bf16x4*)&A2t[col][j * 4];
    __bf16* bnd0 = bnd + ((size_t)2 * blockIdx.x) * 256 + col;
    float sum = 0.f;
    int s0 = 0;
#pragma unroll
    for (int r = 0; r < 64; ++r) {
      sum += (float)v[r >> 2][r & 3];
      if (r == 63 || ((mask >> (r + 1)) & 1ull)) {
        const bool isFirst = (s0 == 0), isLast = (r == 63);
        if (isFirst) {
          bnd0[0] = (__bf16)(isLast ? 0.f : sum);
          if (isLast) bnd0[256] = (__bf16)sum;
        } else if (isLast) {
          bnd0[256] = (__bf16)sum;
        } else {
          agg[(size_t)sDst[r] * H + col] = (__bf16)sum;
        }
        sum = 0.f;
        s0 = r + 1;
      }
    }
  }
}

// ---------------------------------------------------------------------------
// Fused node update + (mode 0) next-layer PS/PD or (mode 1) output proj.
// h staged from fragment layout; agg/bnd bf16; all h/P stores coalesced.
// ---------------------------------------------------------------------------
__global__ __launch_bounds__(256, 3) void node_kernel(
    __bf16* __restrict__ h, const __bf16* __restrict__ agg,
    const __bf16* __restrict__ bnd, const int* __restrict__ cnt2,
    const int* __restrict__ nrole, const int* __restrict__ ncol,
    const __bf16* __restrict__ n1p, const __bf16* __restrict__ TNp,
    const __bf16* __restrict__ n2p, const float* __restrict__ n2b,
    const float* __restrict__ lng, const float* __restrict__ lnb,
    const int mode,
    const __bf16* __restrict__ wsdN, const __bf16* __restrict__ TSpN,
    const __bf16* __restrict__ TDpN, __bf16* __restrict__ PS, __bf16* __restrict__ PD,
    const __bf16* __restrict__ outp, const float* __restrict__ outb,
    float* __restrict__ out)
{
  __shared__ __align__(16) char uni[37888];
  __shared__ float sSum[64][4], sSsq[64][4];
  __shared__ int sTi[64], sPcnt[64], sPidx[64][4];

  auto Abuf = (__bf16 (*)[72])uni;   // [64][72]   GEMM1 staging
  auto A2   = (__bf16 (*)[296])uni;  // [64][296]  GEMM1 out / h_new + onehot

  const int tid  = threadIdx.x;
  const int lane = tid & 63;
  const int wave = tid >> 6;
  const int l15  = lane & 15;
  const int quad = lane >> 4;
  const int n0   = blockIdx.x * 64;
  const int colW = wave * 64;
  const int fb   = (blockIdx.x << 14) + (wave << 12);   // fragment-store base

  if (tid < 64) {
    const int n = n0 + tid;
    int st = 0, en = 0, ti = 0;
    if (n < NN) {
      st = cnt2[n];
      en = cnt2[n + 1];
      ti = nrole[n] * 3 + ncol[n];
    }
    sTi[tid] = ti;
    int pc = 0, pidx[4] = {0, 0, 0, 0};
    if (en > st) {
      const int bs = st >> 6, be = (en - 1) >> 6;
      if (bs == be && (st & 63) != 0 && (en & 63) != 0) {
        pc = -1;                       // strictly interior: read agg row
      } else {
        for (int b = bs; b <= be && pc < 4; ++b) {
          if (b > bs || (st & 63) == 0) pidx[pc++] = 2 * b;
          if ((b < be || (en & 63) == 0) && pc < 4) pidx[pc++] = 2 * b + 1;
        }
      }
    }
    sPcnt[tid] = pc;
#pragma unroll
    for (int j = 0; j < 4; ++j) sPidx[tid][j] = pidx[j];
  }
  __syncthreads();

  // identity B-fragments for residual
  bf16x8 ibfr[2];
#pragma unroll
  for (int t = 0; t < 2; ++t)
#pragma unroll
    for (int j = 0; j < 8; ++j)
      ibfr[t][j] = (__bf16)((quad * 8 + j == t * 16 + l15) ? 1.f : 0.f);

  f32x4 acc[4][4] = {};
  f32x4 acch[4][4] = {};
  for (int s = 0; s < 8; ++s) {
    if (s) __syncthreads();
    if (s < 4) {
#pragma unroll
      for (int it = 0; it < 2; ++it) {
        const int t = tid + it * 256;
        const int row = t >> 3, seg = t & 7;
        const int n = n0 + row;
        bf16x8 v = bzero8();
        if (n < NN) {
          const int a = (blockIdx.x << 14) + (s << 12) + ((row >> 4) << 10) +
                        ((seg >> 1) << 8) + ((row & 3) << 6) +
                        (((row >> 2) & 3) << 4) + ((seg & 1) << 3);
          v = *(const bf16x8*)(h + a);
        }
        *(bf16x8*)&Abuf[row][seg * 8] = v;
      }
    } else {
#pragma unroll
      for (int it = 0; it < 2; ++it) {
        const int t = tid + it * 256;
        const int row = t >> 3, seg = t & 7;
        const int off = (s - 4) * 64 + seg * 8;
        const int pc = sPcnt[row];
        bf16x8 v = bzero8();
        if (pc == -1) {
          v = *(const bf16x8*)(agg + (size_t)(n0 + row) * H + off);
        } else if (pc > 0) {
          float a8[8] = {0.f, 0.f, 0.f, 0.f, 0.f, 0.f, 0.f, 0.f};
          for (int j = 0; j < pc; ++j) {
            const bf16x8 pv = *(const bf16x8*)(bnd + (size_t)sPidx[row][j] * 256 + off);
#pragma unroll
            for (int k = 0; k < 8; ++k) a8[k] += (float)pv[k];
          }
#pragma unroll
          for (int k = 0; k < 8; ++k) v[k] = (__bf16)a8[k];
        }
        *(bf16x8*)&Abuf[row][seg * 8] = v;
      }
    }
    __syncthreads();
#pragma unroll
    for (int cc = 0; cc < 2; ++cc) {
      const int c = 2 * s + cc;
      bf16x8 bfr[4], afr[4];
#pragma unroll
      for (int nj = 0; nj < 4; ++nj)
        bfr[nj] = *(const bf16x8*)(n1p + ((size_t)c * 256 + colW + nj * 16 + l15) * 32 + quad * 8);
#pragma unroll
      for (int mi = 0; mi < 4; ++mi)
        afr[mi] = *(const bf16x8*)&Abuf[mi * 16 + l15][cc * 32 + quad * 8];
#pragma unroll
      for (int mi = 0; mi < 4; ++mi)
#pragma unroll
        for (int nj = 0; nj < 4; ++nj)
          acc[mi][nj] = mfma16(afr[mi], bfr[nj], acc[mi][nj]);
      if (s == wave) {   // residual: h columns of this wave, identity B
#pragma unroll
        for (int t = 0; t < 2; ++t)
#pragma unroll
          for (int mi = 0; mi < 4; ++mi)
            acch[mi][cc * 2 + t] = mfma16(afr[mi], ibfr[t], acch[mi][cc * 2 + t]);
      }
    }
  }
  // onehot stage -> chunk 16 (TNp table add, includes n1b)
  __syncthreads();
  {
    const int row = tid >> 2, q = tid & 3;
    const int ti = sTi[row];
    bf16x8 v;
#pragma unroll
    for (int j = 0; j < 8; ++j) v[j] = (__bf16)((q * 8 + j == ti) ? 1.f : 0.f);
    *(bf16x8*)&Abuf[row][q * 8] = v;
  }
  __syncthreads();
  {
    bf16x8 bfr[4], afr[4];
#pragma unroll
    for (int nj = 0; nj < 4; ++nj)
      bfr[nj] = *(const bf16x8*)(TNp + ((size_t)(colW + nj * 16 + l15)) * 32 + quad * 8);
#pragma unroll
    for (int mi = 0; mi < 4; ++mi)
      afr[mi] = *(const bf16x8*)&Abuf[mi * 16 + l15][quad * 8];
#pragma unroll
    for (int mi = 0; mi < 4; ++mi)
#pragma unroll
      for (int nj = 0; nj < 4; ++nj)
        acc[mi][nj] = mfma16(afr[mi], bfr[nj], acc[mi][nj]);
  }
  __syncthreads();   // Abuf reads done before A2 (aliased) write

  // GEMM1 epilogue: silu -> A2
#pragma unroll
  for (int mi = 0; mi < 4; ++mi)
#pragma unroll
    for (int r = 0; r < 4; ++r) {
      const int row = mi * 16 + quad * 4 + r;
#pragma unroll
      for (int nj = 0; nj < 4; ++nj)
        A2[row][colW + nj * 16 + l15] = (__bf16)silu_f(acc[mi][nj][r]);
    }
  __syncthreads();

  f32x4 acc2[4][4] = {};
#pragma unroll
  for (int c = 0; c < 8; ++c) {
    bf16x8 bfr[4], afr[4];
#pragma unroll
    for (int nj = 0; nj < 4; ++nj)
      bfr[nj] = *(const bf16x8*)(n2p + ((size_t)c * 256 + colW + nj * 16 + l15) * 32 + quad * 8);
#pragma unroll
    for (int mi = 0; mi < 4; ++mi)
      afr[mi] = *(const bf16x8*)&A2[mi * 16 + l15][c * 32 + quad * 8];
#pragma unroll
    for (int mi = 0; mi < 4; ++mi)
#pragma unroll
      for (int nj = 0; nj < 4; ++nj)
        acc2[mi][nj] = mfma16(afr[mi], bfr[nj], acc2[mi][nj]);
  }

  float b2[4], g4[4], bb4[4];
#pragma unroll
  for (int nj = 0; nj < 4; ++nj) {
    const int col = colW + nj * 16 + l15;
    b2[nj] = n2b[col]; g4[nj] = lng[col]; bb4[nj] = lnb[col];
  }
#pragma unroll
  for (int mi = 0; mi < 4; ++mi)
#pragma unroll
    for (int nj = 0; nj < 4; ++nj)
#pragma unroll
      for (int r = 0; r < 4; ++r)
        acc2[mi][nj][r] += b2[nj] + acch[mi][nj][r];

#pragma unroll
  for (int mi = 0; mi < 4; ++mi)
#pragma unroll
    for (int r = 0; r < 4; ++r) {
      float s1 = 0.f, s2 = 0.f;
#pragma unroll
      for (int nj = 0; nj < 4; ++nj) {
        const float v = acc2[mi][nj][r];
        s1 += v; s2 += v * v;
      }
#pragma unroll
      for (int d = 1; d < 16; d <<= 1) {
        s1 += __shfl_xor(s1, d, 16);
        s2 += __shfl_xor(s2, d, 16);
      }
      if (l15 == 0) {
        const int row = mi * 16 + quad * 4 + r;
        sSum[row][wave] = s1; sSsq[row][wave] = s2;
      }
    }
  __syncthreads();   // also: GEMM2 A2 reads complete -> A2 reusable as h_new

#pragma unroll
  for (int mi = 0; mi < 4; ++mi)
#pragma unroll
    for (int r = 0; r < 4; ++r) {
      const int row = mi * 16 + quad * 4 + r;
      const float t1 = sSum[row][0] + sSum[row][1] + sSum[row][2] + sSum[row][3];
      const float t2 = sSsq[row][0] + sSsq[row][1] + sSsq[row][2] + sSsq[row][3];
      const float mu = t1 * (1.f / 256.f);
      float var = t2 * (1.f / 256.f) - mu * mu;
      var = var < 0.f ? 0.f : var;
      const float rstd = rsqrtf(var + 1e-5f);
#pragma unroll
      for (int nj = 0; nj < 4; ++nj) {
        const float o = g4[nj] * (acc2[mi][nj][r] - mu) * rstd + bb4[nj];
        const __bf16 ob = (__bf16)o;
        A2[row][colW + nj * 16 + l15] = ob;
        if (mode == 0) h[fb + (mi << 10) + ((nj * 4 + r) << 6) + lane] = ob;
      }
    }
  // onehot into A2 cols 256..287 for the P-GEMM table chunk
  if (mode == 0) {
    const int row = tid >> 2, q = tid & 3;
    const int ti = sTi[row];
    bf16x8 v;
#pragma unroll
    for (int j = 0; j < 8; ++j) v[j] = (__bf16)((q * 8 + j == ti) ? 1.f : 0.f);
    *(bf16x8*)&A2[row][256 + q * 8] = v;
  }
  __syncthreads();   // h_new (+onehot) staged in A2

  if (mode == 0) {
    for (int hf = 0; hf < 2; ++hf) {
      f32x4 ap[4][4] = {};
#pragma unroll
      for (int c = 0; c < 9; ++c) {
        bf16x8 bfr[4], afr[4];
        const __bf16* bp = (c < 8)
            ? wsdN + ((size_t)c * 512 + hf * 256) * 32
            : (hf ? TDpN : TSpN);
#pragma unroll
        for (int nj = 0; nj < 4; ++nj)
          bfr[nj] = *(const bf16x8*)(bp + ((size_t)(colW + nj * 16 + l15)) * 32 + quad * 8);
#pragma unroll
        for (int mi = 0; mi < 4; ++mi)
          afr[mi] = *(const bf16x8*)&A2[mi * 16 + l15][c * 32 + quad * 8];
#pragma unroll
        for (int mi = 0; mi < 4; ++mi)
#pragma unroll
          for (int nj = 0; nj < 4; ++nj)
            ap[mi][nj] = mfma16(afr[mi], bfr[nj], ap[mi][nj]);
      }
      __bf16* P = hf ? PD : PS;
#pragma unroll
      for (int mi = 0; mi < 4; ++mi)
#pragma unroll
        for (int nj = 0; nj < 4; ++nj)
#pragma unroll
          for (int r = 0; r < 4; ++r)
            P[fb + (mi << 10) + ((nj * 4 + r) << 6) + lane] = (__bf16)ap[mi][nj][r];
    }
  } else {
    f32x4 ao[4] = {};
#pragma unroll
    for (int c = 0; c < 8; ++c) {
      const bf16x8 bfr = *(const bf16x8*)(outp + ((size_t)c * 64 + wave * 16 + l15) * 32 + quad * 8);
#pragma unroll
      for (int mi = 0; mi < 4; ++mi) {
        const bf16x8 afr = *(const bf16x8*)&A2[mi * 16 + l15][c * 32 + quad * 8];
        ao[mi] = mfma16(afr, bfr, ao[mi]);
      }
    }
    const float ob = outb[wave * 16 + l15];
#pragma unroll
    for (int mi = 0; mi < 4; ++mi)
#pragma unroll
      for (int r = 0; r < 4; ++r) {
        const int n = n0 + mi * 16 + quad * 4 + r;
        if (n < NN) out[(size_t)n * 64 + wave * 16 + l15] = ao[mi][r] + ob;
      }
  }
}

// ---------------------------------------------------------------------------
extern "C" void kernel_launch(void* const* d_in, const int* in_sizes, int n_in,
                              void* d_out, int out_size, void* d_ws, size_t ws_size,
                              hipStream_t stream) {
  const float* scalars   = (const float*)d_in[0];
  const int*   ei        = (const int*)d_in[1];
  const int*   erel      = (const int*)d_in[2];
  const int*   ncol      = (const int*)d_in[3];
  const int*   nrole     = (const int*)d_in[4];
  const float* blk_role  = (const float*)d_in[5];
  const float* blk_col   = (const float*)d_in[6];
  const float* inw       = (const float*)d_in[7];
  const float* inb       = (const float*)d_in[8];
  const float* rel_embs  = (const float*)d_in[9];
  const float* role_embs = (const float*)d_in[10];
  const float* col_embs  = (const float*)d_in[11];
  const float* e1w       = (const float*)d_in[12];
  const float* e1b       = (const float*)d_in[13];
  const float* e2w       = (const float*)d_in[14];
  const float* e2b       = (const float*)d_in[15];
  const float* n1w       = (const float*)d_in[16];
  const float* n1b       = (const float*)d_in[17];
  const float* n2w       = (const float*)d_in[18];
  const float* n2b       = (const float*)d_in[19];
  const float* lng       = (const float*)d_in[20];
  const float* lnb       = (const float*)d_in[21];
  const float* outw      = (const float*)d_in[22];
  const float* outb      = (const float*)d_in[23];

  const int* srcI = ei;
  const int* dstI = ei + NE;

  char* ws = (char*)d_ws;
  size_t off = 0;
  auto take = [&](size_t bytes) -> char* {
    off = (off + 255) & ~(size_t)255;
    char* p = ws + off;
    off += bytes;
    return p;
  };
  __bf16* h    = (__bf16*)take((size_t)HBLK * 16384 * 2);   // fragment layout
  __bf16* agg  = (__bf16*)take((size_t)NN * H * 2);
  __bf16* bnd  = (__bf16*)take((size_t)2 * NB * 256 * 2);
  __bf16* PS   = (__bf16*)take((size_t)HBLK * 16384 * 2);   // fragment layout
  __bf16* PD   = (__bf16*)take((size_t)HBLK * 16384 * 2);   // fragment layout
  __bf16* wsd  = (__bf16*)take((size_t)3 * 131072 * 2);
  __bf16* e2p  = (__bf16*)take((size_t)3 * 65536 * 2);
  __bf16* n1p  = (__bf16*)take((size_t)3 * 131072 * 2);
  __bf16* n2p  = (__bf16*)take((size_t)3 * 65536 * 2);
  __bf16* outp = (__bf16*)take((size_t)16384 * 2);
  float*  TR   = (float*)take((size_t)3 * 8 * 256 * 4);
  __bf16* TNp  = (__bf16*)take((size_t)3 * 8192 * 2);
  __bf16* TSp  = (__bf16*)take((size_t)3 * 8192 * 2);
  __bf16* TDp  = (__bf16*)take((size_t)3 * 8192 * 2);
  int*    cnt  = (int*)take((size_t)NBINS * 4);
  int*    cnt2 = (int*)take((size_t)NBINS * 4);
  int*    perm = (int*)take((size_t)NE * 4);
  int*    dstS = (int*)take((size_t)NE * 4);

  hipMemsetAsync(cnt, 0, (size_t)NBINS * 4, stream);
  preph_kernel<<<7800, 256, 0, stream>>>(
      e1w, e2w, n1w, n2w, outw, e1b, n1b, rel_embs, role_embs, col_embs, dstI,
      wsd, e2p, n1p, n2p, outp, cnt, TR, TNp, TSp, TDp);
  scan_kernel<<<1, 1024, 0, stream>>>(cnt, cnt2);
  scem_kernel<<<4103, 256, 0, stream>>>(
      dstI, cnt, cnt2, perm, dstS,
      scalars, ncol, nrole, blk_col, blk_role, inw, inb,
      wsd, TSp, TDp, h, PS, PD);

  for (int l = 0; l < 3; ++l) {
    edge_kernel<<<NB, 256, 0, stream>>>(
        PS, PD, agg, bnd, perm, dstS, srcI, erel, TR + (size_t)l * 2048,
        e2p + (size_t)l * 65536, e2b + (size_t)l * 256);
    const int mode = (l < 2) ? 0 : 1;
    const int ln = (l + 1 < 3) ? l + 1 : 0;
    node_kernel<<<HBLK, 256, 0, stream>>>(
        h, agg, bnd, cnt2, nrole, ncol,
        n1p + (size_t)l * 131072, TNp + (size_t)l * 8192,
        n2p + (size_t)l * 65536,  n2b + (size_t)l * 256,
        lng + (size_t)l * 256, lnb + (size_t)l * 256,
        mode,
        wsd + (size_t)ln * 131072, TSp + (size_t)ln * 8192, TDp + (size_t)ln * 8192,
        PS, PD, outp, outb, (float*)d_out);
  }
}

// Round 9
// 1169.405 us; speedup vs baseline: 1.3640x; 1.3640x over previous
//
#include <hip/hip_runtime.h>

#define NN 50000
#define NE 800000
#define H 256
#define NB 12500            // edge blocks (64 edges each)
#define NBINS 50176         // NN padded
#define HBLK 782            // node blocks (64 nodes each)

typedef __bf16 bf16x8 __attribute__((ext_vector_type(8)));
typedef __bf16 bf16x4 __attribute__((ext_vector_type(4)));
typedef float f32x4 __attribute__((ext_vector_type(4)));

static __device__ __forceinline__ f32x4 mfma16(bf16x8 a, bf16x8 b, f32x4 c) {
  return __builtin_amdgcn_mfma_f32_16x16x32_bf16(a, b, c, 0, 0, 0);
}
static __device__ __forceinline__ bf16x8 bzero8() {
  bf16x8 z;
#pragma unroll
  for (int j = 0; j < 8; ++j) z[j] = (__bf16)0.f;
  return z;
}
static __device__ __forceinline__ float silu_f(float v) {
  return v * __builtin_amdgcn_rcpf(1.f + __builtin_amdgcn_exp2f(v * -1.442695041f));
}

// ---------------------------------------------------------------------------
// prep (blocks 0..4674) + hist (blocks 4675..7799). Same as r8.
// ---------------------------------------------------------------------------
__global__ void preph_kernel(
    const float* __restrict__ e1w, const float* __restrict__ e2w,
    const float* __restrict__ n1w, const float* __restrict__ n2w,
    const float* __restrict__ outw, const float* __restrict__ e1b,
    const float* __restrict__ n1b,
    const float* __restrict__ rel_embs, const float* __restrict__ role_embs,
    const float* __restrict__ col_embs, const int* __restrict__ dstI,
    __bf16* __restrict__ wsd, __bf16* __restrict__ e2p,
    __bf16* __restrict__ n1p, __bf16* __restrict__ n2p,
    __bf16* __restrict__ outp, int* __restrict__ cnt,
    float* __restrict__ TR, __bf16* __restrict__ TNp,
    __bf16* __restrict__ TSp, __bf16* __restrict__ TDp)
{
  if (blockIdx.x >= 4675) {
    const int e = (blockIdx.x - 4675) * 256 + threadIdx.x;
    if (e < NE) atomicAdd(&cnt[dstI[e]], 1);
    return;
  }
  int i = blockIdx.x * 256 + threadIdx.x;
  if (i < 3 * 131072) {
    const int l = i / 131072, rem = i % 131072;
    const int c = rem >> 14, r2 = rem & 16383;
    const int n = r2 >> 5, k = c * 32 + (r2 & 31);
    wsd[i] = (n < 256) ? (__bf16)e1w[((size_t)l * 560 + k) * 256 + n]
                       : (__bf16)e1w[((size_t)l * 560 + 256 + k) * 256 + (n - 256)];
    return;
  }
  i -= 3 * 131072;
  if (i < 3 * 65536) {
    const int l = i / 65536, rem = i % 65536;
    const int c = rem >> 13, r2 = rem & 8191;
    const int n = r2 >> 5, k = c * 32 + (r2 & 31);
    e2p[i] = (__bf16)e2w[((size_t)l * 256 + k) * 256 + n];
    return;
  }
  i -= 3 * 65536;
  if (i < 3 * 131072) {
    const int l = i / 131072, rem = i % 131072;
    const int c = rem >> 13, r2 = rem & 8191;
    const int n = r2 >> 5, k = c * 32 + (r2 & 31);   // k < 512
    n1p[i] = (__bf16)n1w[((size_t)l * 528 + k) * 256 + n];
    return;
  }
  i -= 3 * 131072;
  if (i < 3 * 65536) {
    const int l = i / 65536, rem = i % 65536;
    const int c = rem >> 13, r2 = rem & 8191;
    const int n = r2 >> 5, k = c * 32 + (r2 & 31);
    n2p[i] = (__bf16)n2w[((size_t)l * 256 + k) * 256 + n];
    return;
  }
  i -= 3 * 65536;
  if (i < 16384) {
    const int c = i >> 11, r2 = i & 2047;
    const int n = r2 >> 5, k = c * 32 + (r2 & 31);
    outp[i] = (__bf16)outw[(size_t)k * 64 + n];
    return;
  }
  i -= 16384;
  if (i < 768) {
    const int l = i >> 8, c = i & 255;
    float w[48];
#pragma unroll
    for (int j = 0; j < 48; ++j) w[j] = e1w[((size_t)l * 560 + 512 + j) * 256 + c];
#pragma unroll
    for (int r = 0; r < 8; ++r) {
      float s = 0.f;
#pragma unroll
      for (int j = 0; j < 16; ++j) s += rel_embs[l * 128 + r * 16 + j] * w[j];
      TR[((size_t)l * 8 + r) * 256 + c] = s;
    }
    float wn[16];
#pragma unroll
    for (int j = 0; j < 16; ++j) wn[j] = n1w[((size_t)l * 528 + 512 + j) * 256 + c];
    const float bias = e1b[l * 256 + c];
    const float nbias = n1b[l * 256 + c];
    const size_t ob = ((size_t)l * 256 + c) * 32;
#pragma unroll
    for (int ro = 0; ro < 8; ++ro) {
      float ss = 0.f, sd = 0.f, sn = 0.f;
#pragma unroll
      for (int j = 0; j < 8; ++j) {
        const float re = role_embs[l * 64 + ro * 8 + j];
        ss += re * w[16 + j];
        sd += re * w[24 + j];
        sn += re * wn[j];
      }
#pragma unroll
      for (int co = 0; co < 3; ++co) {
        float cs = 0.f, cd = 0.f, cn = 0.f;
#pragma unroll
        for (int j = 0; j < 8; ++j) {
          const float ce = col_embs[l * 24 + co * 8 + j];
          cs += ce * w[32 + j];
          cd += ce * w[40 + j];
          cn += ce * wn[8 + j];
        }
        const int k = ro * 3 + co;
        TSp[ob + k] = (__bf16)(ss + cs);
        TDp[ob + k] = (__bf16)(sd + cd + bias);
        TNp[ob + k] = (__bf16)(sn + cn + nbias);
      }
    }
#pragma unroll
    for (int k = 24; k < 32; ++k) {
      TSp[ob + k] = (__bf16)0.f;
      TDp[ob + k] = (__bf16)0.f;
      TNp[ob + k] = (__bf16)0.f;
    }
  }
}

// ---------------------------------------------------------------------------
// Scan: cnt -> exclusive prefix (in place) + stable copy cnt2.
// ---------------------------------------------------------------------------
__global__ __launch_bounds__(1024) void scan_kernel(int* __restrict__ cnt,
                                                    int* __restrict__ cnt2) {
  __shared__ int wsum[16];
  __shared__ int carry;
  const int tid = threadIdx.x, lane = tid & 63, wid = tid >> 6;
  if (tid == 0) carry = 0;
  __syncthreads();
  for (int base = 0; base < NBINS; base += 4096) {
    const int idx = base + tid * 4;
    int4 v = make_int4(0, 0, 0, 0);
    if (idx < NBINS) v = *(const int4*)&cnt[idx];
    const int s1 = v.x + v.y, s2 = s1 + v.z, tot = s2 + v.w;
    int x = tot;
#pragma unroll
    for (int d = 1; d < 64; d <<= 1) {
      const int y = __shfl_up(x, d, 64);
      if (lane >= d) x += y;
    }
    if (lane == 63) wsum[wid] = x;
    __syncthreads();
    int wpref = 0;
#pragma unroll
    for (int w = 0; w < 16; ++w)
      if (w < wid) wpref += wsum[w];
    const int ex = carry + wpref + (x - tot);
    if (idx < NBINS) {
      int4 o;
      o.x = ex; o.y = ex + v.x; o.z = ex + s1; o.w = ex + s2;
      *(int4*)&cnt[idx] = o;
      *(int4*)&cnt2[idx] = o;
    }
    __syncthreads();
    if (tid == 0) {
      int s = 0;
#pragma unroll
      for (int w = 0; w < 16; ++w) s += wsum[w];
      carry += s;
    }
    __syncthreads();
  }
}

// ---------------------------------------------------------------------------
// scatter perm (blocks 0..3124) + dstS run-fill (3125..3320).
// ---------------------------------------------------------------------------
__global__ void scat_kernel(const int* __restrict__ dstI, int* __restrict__ cnt,
                            const int* __restrict__ cnt2,
                            int* __restrict__ perm, int* __restrict__ dstS) {
  if (blockIdx.x >= 3125) {
    const int n = (blockIdx.x - 3125) * 256 + threadIdx.x;
    if (n < NN) {
      const int st = cnt2[n], en = cnt2[n + 1];
      for (int p = st; p < en; ++p) dstS[p] = n;
    }
    return;
  }
  const int e = blockIdx.x * 256 + threadIdx.x;
  if (e < NE) {
    const int pos = atomicAdd(&cnt[dstI[e]], 1);
    perm[pos] = e;
  }
}

// ---------------------------------------------------------------------------
// Embed + layer-0 PS/PD. Row-major h/PS/PD; all global stores coalesced via
// LDS round-trip (Hs).
// ---------------------------------------------------------------------------
__global__ __launch_bounds__(256, 2) void embed_kernel(
    const float* __restrict__ scalars, const int* __restrict__ ncol,
    const int* __restrict__ nrole,
    const float* __restrict__ colEmb, const float* __restrict__ roleEmb,
    const float* __restrict__ inw, const float* __restrict__ inb,
    const __bf16* __restrict__ wsd,
    const __bf16* __restrict__ TSp, const __bf16* __restrict__ TDp,
    __bf16* __restrict__ h, __bf16* __restrict__ PS, __bf16* __restrict__ PD)
{
  __shared__ __align__(16) char uni[37888];
  __shared__ int sTi[64];
  auto Ain = (__bf16 (*)[40])uni;    // [64][40] input features
  auto Hs  = (__bf16 (*)[296])uni;   // [64][296] h tile + onehot (aliased)

  const int tid  = threadIdx.x;
  const int lane = tid & 63;
  const int wave = tid >> 6;
  const int l15  = lane & 15;
  const int quad = lane >> 4;
  const int n0   = blockIdx.x * 64;
  const int colW = wave * 64;
  const int rowS = tid >> 5, colS = (tid & 31) * 8;   // coalesced-store coords

  if (tid < 64) {
    const int n = n0 + tid;
    sTi[tid] = (n < NN) ? (nrole[n] * 3 + ncol[n]) : 0;
  }
  {
    const int row = tid >> 2, q = tid & 3;
    const int n = n0 + row;
    __bf16* dp = &Ain[row][q * 8];
    if (n < NN) {
      if (q < 2) {
#pragma unroll
        for (int j = 0; j < 8; ++j) dp[j] = (__bf16)scalars[(size_t)n * 16 + q * 8 + j];
      } else if (q == 2) {
        const int c = ncol[n];
#pragma unroll
        for (int j = 0; j < 8; ++j) dp[j] = (__bf16)colEmb[c * 8 + j];
      } else {
        const int r = nrole[n];
#pragma unroll
        for (int j = 0; j < 8; ++j) dp[j] = (__bf16)roleEmb[r * 8 + j];
      }
    } else {
#pragma unroll
      for (int j = 0; j < 8; ++j) dp[j] = (__bf16)0.f;
    }
  }
  __syncthreads();

  // h-GEMM: single K=32 chunk
  f32x4 acc[4][4] = {};
  {
    bf16x8 bfr[4], afr[4];
#pragma unroll
    for (int nj = 0; nj < 4; ++nj) {
      const int col = colW + nj * 16 + l15;
#pragma unroll
      for (int j = 0; j < 8; ++j) bfr[nj][j] = (__bf16)inw[(quad * 8 + j) * 256 + col];
    }
#pragma unroll
    for (int mi = 0; mi < 4; ++mi)
      afr[mi] = *(const bf16x8*)&Ain[mi * 16 + l15][quad * 8];
#pragma unroll
    for (int mi = 0; mi < 4; ++mi)
#pragma unroll
      for (int nj = 0; nj < 4; ++nj)
        acc[mi][nj] = mfma16(afr[mi], bfr[nj], acc[mi][nj]);
  }
  float bi[4];
#pragma unroll
  for (int nj = 0; nj < 4; ++nj) bi[nj] = inb[colW + nj * 16 + l15];
  __syncthreads();   // Ain reads done before Hs (aliased) write

#pragma unroll
  for (int mi = 0; mi < 4; ++mi)
#pragma unroll
    for (int r = 0; r < 4; ++r) {
      const int row = mi * 16 + quad * 4 + r;
#pragma unroll
      for (int nj = 0; nj < 4; ++nj)
        Hs[row][colW + nj * 16 + l15] = (__bf16)(acc[mi][nj][r] + bi[nj]);
    }
  // onehot into Hs cols 256..287
  {
    const int row = tid >> 2, q = tid & 3;
    const int ti = sTi[row];
    bf16x8 v;
#pragma unroll
    for (int j = 0; j < 8; ++j) v[j] = (__bf16)((q * 8 + j == ti) ? 1.f : 0.f);
    *(bf16x8*)&Hs[row][256 + q * 8] = v;
  }
  __syncthreads();

  // coalesced h store from Hs (512B-contiguous per row)
#pragma unroll
  for (int it = 0; it < 8; ++it) {
    const int row = it * 8 + rowS;
    const int n = n0 + row;
    if (n < NN)
      *(bf16x8*)(h + (size_t)n * H + colS) = *(const bf16x8*)&Hs[row][colS];
  }

  // P-GEMMs: both halves into registers while Hs intact
  f32x4 ap0[4][4] = {}, ap1[4][4] = {};
#pragma unroll
  for (int c = 0; c < 9; ++c) {
    bf16x8 afr[4];
#pragma unroll
    for (int mi = 0; mi < 4; ++mi)
      afr[mi] = *(const bf16x8*)&Hs[mi * 16 + l15][c * 32 + quad * 8];
    const __bf16* bp0 = (c < 8) ? wsd + ((size_t)c * 512) * 32 : TSp;
    const __bf16* bp1 = (c < 8) ? wsd + ((size_t)c * 512 + 256) * 32 : TDp;
#pragma unroll
    for (int nj = 0; nj < 4; ++nj) {
      const bf16x8 b0 = *(const bf16x8*)(bp0 + ((size_t)(colW + nj * 16 + l15)) * 32 + quad * 8);
      const bf16x8 b1 = *(const bf16x8*)(bp1 + ((size_t)(colW + nj * 16 + l15)) * 32 + quad * 8);
#pragma unroll
      for (int mi = 0; mi < 4; ++mi) {
        ap0[mi][nj] = mfma16(afr[mi], b0, ap0[mi][nj]);
        ap1[mi][nj] = mfma16(afr[mi], b1, ap1[mi][nj]);
      }
    }
  }
  __syncthreads();   // Hs reads done

  // stage ap0 -> Hs, coalesced PS store; then ap1 -> PD
#pragma unroll
  for (int hf = 0; hf < 2; ++hf) {
    if (hf) __syncthreads();
#pragma unroll
    for (int mi = 0; mi < 4; ++mi)
#pragma unroll
      for (int r = 0; r < 4; ++r) {
        const int row = mi * 16 + quad * 4 + r;
#pragma unroll
        for (int nj = 0; nj < 4; ++nj)
          Hs[row][colW + nj * 16 + l15] =
              (__bf16)(hf ? ap1[mi][nj][r] : ap0[mi][nj][r]);
      }
    __syncthreads();
    __bf16* P = hf ? PD : PS;
#pragma unroll
    for (int it = 0; it < 8; ++it) {
      const int row = it * 8 + rowS;
      const int n = n0 + row;
      if (n < NN)
        *(bf16x8*)(P + (size_t)n * H + colS) = *(const bf16x8*)&Hs[row][colS];
    }
  }
}

// ---------------------------------------------------------------------------
// Fused edge MLP + segmented scatter (sorted by dst, no atomics).
// Row-major PS/PD gathers; bf16 agg/bnd stores.
// ---------------------------------------------------------------------------
__global__ __launch_bounds__(256, 4) void edge_kernel(
    const __bf16* __restrict__ PS, const __bf16* __restrict__ PD,
    __bf16* __restrict__ agg, __bf16* __restrict__ bnd,
    const int* __restrict__ perm, const int* __restrict__ dstS,
    const int* __restrict__ srcI, const int* __restrict__ erel,
    const float* __restrict__ TR,
    const __bf16* __restrict__ e2p, const float* __restrict__ e2b)
{
  __shared__ __align__(16) char uni[34816];
  __shared__ __bf16 sTrel[8][256];
  __shared__ int sSrc[64], sDst[64], sRel[64];

  auto A2  = (__bf16 (*)[264])uni;      // [64][264]  m1 row-major
  auto A2t = (__bf16 (*)[68])uni;       // [256][68]  m2 col-major (aliased)

  const int tid  = threadIdx.x;
  const int lane = tid & 63;
  const int wave = tid >> 6;
  const int l15  = lane & 15;
  const int quad = lane >> 4;
  const int e0   = blockIdx.x * 64;
  const int colW = wave * 64;

  if (tid < 64) {
    const int p = perm[e0 + tid];
    sSrc[tid] = srcI[p];
    sRel[tid] = erel[p];
    sDst[tid] = dstS[e0 + tid];
  }
  {
    const int r = tid >> 5, cs = (tid & 31) * 8;
    const float* p = TR + r * 256 + cs;
    bf16x8 v;
#pragma unroll
    for (int j = 0; j < 8; ++j) v[j] = (__bf16)p[j];
    *(bf16x8*)&sTrel[r][cs] = v;
  }
  __syncthreads();

  // ---- m1 ----
  {
    const int brow = tid >> 5;
    const int cs = (tid & 31) * 8;
#pragma unroll
    for (int it = 0; it < 8; ++it) {
      const int row = it * 8 + brow;
      const bf16x8 a = *(const bf16x8*)(PS + (size_t)sSrc[row] * H + cs);
      const bf16x8 b = *(const bf16x8*)(PD + (size_t)sDst[row] * H + cs);
      const bf16x8 t = *(const bf16x8*)&sTrel[sRel[row]][cs];
      bf16x8 o;
#pragma unroll
      for (int j = 0; j < 8; ++j)
        o[j] = (__bf16)silu_f((float)a[j] + (float)b[j] + (float)t[j]);
      *(bf16x8*)&A2[row][cs] = o;
    }
  }
  __syncthreads();

  // ---- GEMM2 ----
  f32x4 acc2[4][4] = {};
#pragma unroll
  for (int c = 0; c < 8; ++c) {
    bf16x8 bfr[4], afr[4];
#pragma unroll
    for (int nj = 0; nj < 4; ++nj)
      bfr[nj] = *(const bf16x8*)(e2p + ((size_t)c * 256 + colW + nj * 16 + l15) * 32 + quad * 8);
#pragma unroll
    for (int mi = 0; mi < 4; ++mi)
      afr[mi] = *(const bf16x8*)&A2[mi * 16 + l15][c * 32 + quad * 8];
#pragma unroll
    for (int mi = 0; mi < 4; ++mi)
#pragma unroll
      for (int nj = 0; nj < 4; ++nj)
        acc2[mi][nj] = mfma16(afr[mi], bfr[nj], acc2[mi][nj]);
  }

  float b2[4];
#pragma unroll
  for (int nj = 0; nj < 4; ++nj) b2[nj] = e2b[colW + nj * 16 + l15];
  __syncthreads();   // A2 reads done before A2t (aliased) write

#pragma unroll
  for (int mi = 0; mi < 4; ++mi)
#pragma unroll
    for (int nj = 0; nj < 4; ++nj) {
      const int col = colW + nj * 16 + l15;
      bf16x4 pv;
#pragma unroll
      for (int r = 0; r < 4; ++r)
        pv[r] = (__bf16)silu_f(acc2[mi][nj][r] + b2[nj]);
      *(bf16x4*)&A2t[col][mi * 16 + quad * 4] = pv;
    }
  __syncthreads();

  // ---- segmented reduce: thread = column; all plain stores (bf16) ----
  {
    const int col = tid;
    const bool f = (lane > 0) && (sDst[lane] != sDst[lane - 1]);
    const unsigned long long mask = __ballot(f);
    bf16x4 v[16];
#pragma unroll
    for (int j = 0; j < 16; ++j) v[j] = *(const bf16x4*)&A2t[col][j * 4];
    __bf16* bnd0 = bnd + ((size_t)2 * blockIdx.x) * 256 + col;
    float sum = 0.f;
    int s0 = 0;
#pragma unroll
    for (int r = 0; r < 64; ++r) {
      sum += (float)v[r >> 2][r & 3];
      if (r == 63 || ((mask >> (r + 1)) & 1ull)) {
        const bool isFirst = (s0 == 0), isLast = (r == 63);
        if (isFirst) {
          bnd0[0] = (__bf16)(isLast ? 0.f : sum);
          if (isLast) bnd0[256] = (__bf16)sum;
        } else if (isLast) {
          bnd0[256] = (__bf16)sum;
        } else {
          agg[(size_t)sDst[r] * H + col] = (__bf16)sum;
        }
        sum = 0.f;
        s0 = r + 1;
      }
    }
  }
}

// ---------------------------------------------------------------------------
// Fused node update + (mode 0) next-layer PS/PD or (mode 1) output proj.
// Row-major h; all h/P stores coalesced via LDS (A2) round-trip.
// ---------------------------------------------------------------------------
__global__ __launch_bounds__(256, 2) void node_kernel(
    __bf16* __restrict__ h, const __bf16* __restrict__ agg,
    const __bf16* __restrict__ bnd, const int* __restrict__ cnt2,
    const int* __restrict__ nrole, const int* __restrict__ ncol,
    const __bf16* __restrict__ n1p, const __bf16* __restrict__ TNp,
    const __bf16* __restrict__ n2p, const float* __restrict__ n2b,
    const float* __restrict__ lng, const float* __restrict__ lnb,
    const int mode,
    const __bf16* __restrict__ wsdN, const __bf16* __restrict__ TSpN,
    const __bf16* __restrict__ TDpN, __bf16* __restrict__ PS, __bf16* __restrict__ PD,
    const __bf16* __restrict__ outp, const float* __restrict__ outb,
    float* __restrict__ out)
{
  __shared__ __align__(16) char uni[37888];
  __shared__ float sSum[64][4], sSsq[64][4];
  __shared__ int sTi[64], sPcnt[64], sPidx[64][4];

  auto Abuf = (__bf16 (*)[72])uni;   // [64][72]   GEMM1 staging
  auto A2   = (__bf16 (*)[296])uni;  // [64][296]  GEMM1 out / h_new + onehot

  const int tid  = threadIdx.x;
  const int lane = tid & 63;
  const int wave = tid >> 6;
  const int l15  = lane & 15;
  const int quad = lane >> 4;
  const int n0   = blockIdx.x * 64;
  const int colW = wave * 64;
  const int rowS = tid >> 5, colS = (tid & 31) * 8;

  if (tid < 64) {
    const int n = n0 + tid;
    int st = 0, en = 0, ti = 0;
    if (n < NN) {
      st = cnt2[n];
      en = cnt2[n + 1];
      ti = nrole[n] * 3 + ncol[n];
    }
    sTi[tid] = ti;
    int pc = 0, pidx[4] = {0, 0, 0, 0};
    if (en > st) {
      const int bs = st >> 6, be = (en - 1) >> 6;
      if (bs == be && (st & 63) != 0 && (en & 63) != 0) {
        pc = -1;                       // strictly interior: read agg row
      } else {
        for (int b = bs; b <= be && pc < 4; ++b) {
          if (b > bs || (st & 63) == 0) pidx[pc++] = 2 * b;
          if ((b < be || (en & 63) == 0) && pc < 4) pidx[pc++] = 2 * b + 1;
        }
      }
    }
    sPcnt[tid] = pc;
#pragma unroll
    for (int j = 0; j < 4; ++j) sPidx[tid][j] = pidx[j];
  }
  __syncthreads();

  // identity B-fragments for residual
  bf16x8 ibfr[2];
#pragma unroll
  for (int t = 0; t < 2; ++t)
#pragma unroll
    for (int j = 0; j < 8; ++j)
      ibfr[t][j] = (__bf16)((quad * 8 + j == t * 16 + l15) ? 1.f : 0.f);

  f32x4 acc[4][4] = {};
  f32x4 acch[4][4] = {};
  for (int s = 0; s < 8; ++s) {
    if (s) __syncthreads();
    if (s < 4) {
#pragma unroll
      for (int it = 0; it < 2; ++it) {
        const int t = tid + it * 256;
        const int row = t >> 3, seg = t & 7;
        const int n = n0 + row;
        bf16x8 v = bzero8();
        if (n < NN) v = *(const bf16x8*)(h + (size_t)n * H + s * 64 + seg * 8);
        *(bf16x8*)&Abuf[row][seg * 8] = v;
      }
    } else {
#pragma unroll
      for (int it = 0; it < 2; ++it) {
        const int t = tid + it * 256;
        const int row = t >> 3, seg = t & 7;
        const int off = (s - 4) * 64 + seg * 8;
        const int pc = sPcnt[row];
        bf16x8 v = bzero8();
        if (pc == -1) {
          v = *(const bf16x8*)(agg + (size_t)(n0 + row) * H + off);
        } else if (pc > 0) {
          float a8[8] = {0.f, 0.f, 0.f, 0.f, 0.f, 0.f, 0.f, 0.f};
          for (int j = 0; j < pc; ++j) {
            const bf16x8 pv = *(const bf16x8*)(bnd + (size_t)sPidx[row][j] * 256 + off);
#pragma unroll
            for (int k = 0; k < 8; ++k) a8[k] += (float)pv[k];
          }
#pragma unroll
          for (int k = 0; k < 8; ++k) v[k] = (__bf16)a8[k];
        }
        *(bf16x8*)&Abuf[row][seg * 8] = v;
      }
    }
    __syncthreads();
#pragma unroll
    for (int cc = 0; cc < 2; ++cc) {
      const int c = 2 * s + cc;
      bf16x8 bfr[4], afr[4];
#pragma unroll
      for (int nj = 0; nj < 4; ++nj)
        bfr[nj] = *(const bf16x8*)(n1p + ((size_t)c * 256 + colW + nj * 16 + l15) * 32 + quad * 8);
#pragma unroll
      for (int mi = 0; mi < 4; ++mi)
        afr[mi] = *(const bf16x8*)&Abuf[mi * 16 + l15][cc * 32 + quad * 8];
#pragma unroll
      for (int mi = 0; mi < 4; ++mi)
#pragma unroll
        for (int nj = 0; nj < 4; ++nj)
          acc[mi][nj] = mfma16(afr[mi], bfr[nj], acc[mi][nj]);
      if (s == wave) {   // residual: h columns of this wave, identity B
#pragma unroll
        for (int t = 0; t < 2; ++t)
#pragma unroll
          for (int mi = 0; mi < 4; ++mi)
            acch[mi][cc * 2 + t] = mfma16(afr[mi], ibfr[t], acch[mi][cc * 2 + t]);
      }
    }
  }
  // onehot stage -> chunk 16 (TNp table add, includes n1b)
  __syncthreads();
  {
    const int row = tid >> 2, q = tid & 3;
    const int ti = sTi[row];
    bf16x8 v;
#pragma unroll
    for (int j = 0; j < 8; ++j) v[j] = (__bf16)((q * 8 + j == ti) ? 1.f : 0.f);
    *(bf16x8*)&Abuf[row][q * 8] = v;
  }
  __syncthreads();
  {
    bf16x8 bfr[4], afr[4];
#pragma unroll
    for (int nj = 0; nj < 4; ++nj)
      bfr[nj] = *(const bf16x8*)(TNp + ((size_t)(colW + nj * 16 + l15)) * 32 + quad * 8);
#pragma unroll
    for (int mi = 0; mi < 4; ++mi)
      afr[mi] = *(const bf16x8*)&Abuf[mi * 16 + l15][quad * 8];
#pragma unroll
    for (int mi = 0; mi < 4; ++mi)
#pragma unroll
      for (int nj = 0; nj < 4; ++nj)
        acc[mi][nj] = mfma16(afr[mi], bfr[nj], acc[mi][nj]);
  }
  __syncthreads();   // Abuf reads done before A2 (aliased) write

  // GEMM1 epilogue: silu -> A2
#pragma unroll
  for (int mi = 0; mi < 4; ++mi)
#pragma unroll
    for (int r = 0; r < 4; ++r) {
      const int row = mi * 16 + quad * 4 + r;
#pragma unroll
      for (int nj = 0; nj < 4; ++nj)
        A2[row][colW + nj * 16 + l15] = (__bf16)silu_f(acc[mi][nj][r]);
    }
  __syncthreads();

  f32x4 acc2[4][4] = {};
#pragma unroll
  for (int c = 0; c < 8; ++c) {
    bf16x8 bfr[4], afr[4];
#pragma unroll
    for (int nj = 0; nj < 4; ++nj)
      bfr[nj] = *(const bf16x8*)(n2p + ((size_t)c * 256 + colW + nj * 16 + l15) * 32 + quad * 8);
#pragma unroll
    for (int mi = 0; mi < 4; ++mi)
      afr[mi] = *(const bf16x8*)&A2[mi * 16 + l15][c * 32 + quad * 8];
#pragma unroll
    for (int mi = 0; mi < 4; ++mi)
#pragma unroll
      for (int nj = 0; nj < 4; ++nj)
        acc2[mi][nj] = mfma16(afr[mi], bfr[nj], acc2[mi][nj]);
  }

  float b2[4], g4[4], bb4[4];
#pragma unroll
  for (int nj = 0; nj < 4; ++nj) {
    const int col = colW + nj * 16 + l15;
    b2[nj] = n2b[col]; g4[nj] = lng[col]; bb4[nj] = lnb[col];
  }
#pragma unroll
  for (int mi = 0; mi < 4; ++mi)
#pragma unroll
    for (int nj = 0; nj < 4; ++nj)
#pragma unroll
      for (int r = 0; r < 4; ++r)
        acc2[mi][nj][r] += b2[nj] + acch[mi][nj][r];

#pragma unroll
  for (int mi = 0; mi < 4; ++mi)
#pragma unroll
    for (int r = 0; r < 4; ++r) {
      float s1 = 0.f, s2 = 0.f;
#pragma unroll
      for (int nj = 0; nj < 4; ++nj) {
        const float v = acc2[mi][nj][r];
        s1 += v; s2 += v * v;
      }
#pragma unroll
      for (int d = 1; d < 16; d <<= 1) {
        s1 += __shfl_xor(s1, d, 16);
        s2 += __shfl_xor(s2, d, 16);
      }
      if (l15 == 0) {
        const int row = mi * 16 + quad * 4 + r;
        sSum[row][wave] = s1; sSsq[row][wave] = s2;
      }
    }
  __syncthreads();   // also: GEMM2 A2 reads complete -> A2 reusable as h_new

#pragma unroll
  for (int mi = 0; mi < 4; ++mi)
#pragma unroll
    for (int r = 0; r < 4; ++r) {
      const int row = mi * 16 + quad * 4 + r;
      const float t1 = sSum[row][0] + sSum[row][1] + sSum[row][2] + sSum[row][3];
      const float t2 = sSsq[row][0] + sSsq[row][1] + sSsq[row][2] + sSsq[row][3];
      const float mu = t1 * (1.f / 256.f);
      float var = t2 * (1.f / 256.f) - mu * mu;
      var = var < 0.f ? 0.f : var;
      const float rstd = rsqrtf(var + 1e-5f);
#pragma unroll
      for (int nj = 0; nj < 4; ++nj) {
        const int col = colW + nj * 16 + l15;
        const float o = g4[nj] * (acc2[mi][nj][r] - mu) * rstd + bb4[nj];
        A2[row][col] = (__bf16)o;
      }
    }
  // onehot into A2 cols 256..287 for the P-GEMM table chunk
  if (mode == 0) {
    const int row = tid >> 2, q = tid & 3;
    const int ti = sTi[row];
    bf16x8 v;
#pragma unroll
    for (int j = 0; j < 8; ++j) v[j] = (__bf16)((q * 8 + j == ti) ? 1.f : 0.f);
    *(bf16x8*)&A2[row][256 + q * 8] = v;
  }
  __syncthreads();   // h_new (+onehot) staged in A2

  if (mode == 0) {
    // coalesced h store from A2
#pragma unroll
    for (int it = 0; it < 8; ++it) {
      const int row = it * 8 + rowS;
      const int n = n0 + row;
      if (n < NN)
        *(bf16x8*)(h + (size_t)n * H + colS) = *(const bf16x8*)&A2[row][colS];
    }
    // P-GEMMs: both halves into registers while A2 intact
    f32x4 ap0[4][4] = {}, ap1[4][4] = {};
#pragma unroll
    for (int c = 0; c < 9; ++c) {
      bf16x8 afr[4];
#pragma unroll
      for (int mi = 0; mi < 4; ++mi)
        afr[mi] = *(const bf16x8*)&A2[mi * 16 + l15][c * 32 + quad * 8];
      const __bf16* bp0 = (c < 8) ? wsdN + ((size_t)c * 512) * 32 : TSpN;
      const __bf16* bp1 = (c < 8) ? wsdN + ((size_t)c * 512 + 256) * 32 : TDpN;
#pragma unroll
      for (int nj = 0; nj < 4; ++nj) {
        const bf16x8 b0 = *(const bf16x8*)(bp0 + ((size_t)(colW + nj * 16 + l15)) * 32 + quad * 8);
        const bf16x8 b1 = *(const bf16x8*)(bp1 + ((size_t)(colW + nj * 16 + l15)) * 32 + quad * 8);
#pragma unroll
        for (int mi = 0; mi < 4; ++mi) {
          ap0[mi][nj] = mfma16(afr[mi], b0, ap0[mi][nj]);
          ap1[mi][nj] = mfma16(afr[mi], b1, ap1[mi][nj]);
        }
      }
    }
    __syncthreads();   // A2 reads done
#pragma unroll
    for (int hf = 0; hf < 2; ++hf) {
      if (hf) __syncthreads();
#pragma unroll
      for (int mi = 0; mi < 4; ++mi)
#pragma unroll
        for (int r = 0; r < 4; ++r) {
          const int row = mi * 16 + quad * 4 + r;
#pragma unroll
          for (int nj = 0; nj < 4; ++nj)
            A2[row][colW + nj * 16 + l15] =
                (__bf16)(hf ? ap1[mi][nj][r] : ap0[mi][nj][r]);
        }
      __syncthreads();
      __bf16* P = hf ? PD : PS;
#pragma unroll
      for (int it = 0; it < 8; ++it) {
        const int row = it * 8 + rowS;
        const int n = n0 + row;
        if (n < NN)
          *(bf16x8*)(P + (size_t)n * H + colS) = *(const bf16x8*)&A2[row][colS];
      }
    }
  } else {
    f32x4 ao[4] = {};
#pragma unroll
    for (int c = 0; c < 8; ++c) {
      const bf16x8 bfr = *(const bf16x8*)(outp + ((size_t)c * 64 + wave * 16 + l15) * 32 + quad * 8);
#pragma unroll
      for (int mi = 0; mi < 4; ++mi) {
        const bf16x8 afr = *(const bf16x8*)&A2[mi * 16 + l15][c * 32 + quad * 8];
        ao[mi] = mfma16(afr, bfr, ao[mi]);
      }
    }
    const float ob = outb[wave * 16 + l15];
#pragma unroll
    for (int mi = 0; mi < 4; ++mi)
#pragma unroll
      for (int r = 0; r < 4; ++r) {
        const int n = n0 + mi * 16 + quad * 4 + r;
        if (n < NN) out[(size_t)n * 64 + wave * 16 + l15] = ao[mi][r] + ob;
      }
  }
}

// ---------------------------------------------------------------------------
extern "C" void kernel_launch(void* const* d_in, const int* in_sizes, int n_in,
                              void* d_out, int out_size, void* d_ws, size_t ws_size,
                              hipStream_t stream) {
  const float* scalars   = (const float*)d_in[0];
  const int*   ei        = (const int*)d_in[1];
  const int*   erel      = (const int*)d_in[2];
  const int*   ncol      = (const int*)d_in[3];
  const int*   nrole     = (const int*)d_in[4];
  const float* blk_role  = (const float*)d_in[5];
  const float* blk_col   = (const float*)d_in[6];
  const float* inw       = (const float*)d_in[7];
  const float* inb       = (const float*)d_in[8];
  const float* rel_embs  = (const float*)d_in[9];
  const float* role_embs = (const float*)d_in[10];
  const float* col_embs  = (const float*)d_in[11];
  const float* e1w       = (const float*)d_in[12];
  const float* e1b       = (const float*)d_in[13];
  const float* e2w       = (const float*)d_in[14];
  const float* e2b       = (const float*)d_in[15];
  const float* n1w       = (const float*)d_in[16];
  const float* n1b       = (const float*)d_in[17];
  const float* n2w       = (const float*)d_in[18];
  const float* n2b       = (const float*)d_in[19];
  const float* lng       = (const float*)d_in[20];
  const float* lnb       = (const float*)d_in[21];
  const float* outw      = (const float*)d_in[22];
  const float* outb      = (const float*)d_in[23];

  const int* srcI = ei;
  const int* dstI = ei + NE;

  char* ws = (char*)d_ws;
  size_t off = 0;
  auto take = [&](size_t bytes) -> char* {
    off = (off + 255) & ~(size_t)255;
    char* p = ws + off;
    off += bytes;
    return p;
  };
  __bf16* h    = (__bf16*)take((size_t)NN * H * 2);
  __bf16* agg  = (__bf16*)take((size_t)NN * H * 2);
  __bf16* bnd  = (__bf16*)take((size_t)2 * NB * 256 * 2);
  __bf16* PS   = (__bf16*)take((size_t)NN * H * 2);
  __bf16* PD   = (__bf16*)take((size_t)NN * H * 2);
  __bf16* wsd  = (__bf16*)take((size_t)3 * 131072 * 2);
  __bf16* e2p  = (__bf16*)take((size_t)3 * 65536 * 2);
  __bf16* n1p  = (__bf16*)take((size_t)3 * 131072 * 2);
  __bf16* n2p  = (__bf16*)take((size_t)3 * 65536 * 2);
  __bf16* outp = (__bf16*)take((size_t)16384 * 2);
  float*  TR   = (float*)take((size_t)3 * 8 * 256 * 4);
  __bf16* TNp  = (__bf16*)take((size_t)3 * 8192 * 2);
  __bf16* TSp  = (__bf16*)take((size_t)3 * 8192 * 2);
  __bf16* TDp  = (__bf16*)take((size_t)3 * 8192 * 2);
  int*    cnt  = (int*)take((size_t)NBINS * 4);
  int*    cnt2 = (int*)take((size_t)NBINS * 4);
  int*    perm = (int*)take((size_t)NE * 4);
  int*    dstS = (int*)take((size_t)NE * 4);

  hipMemsetAsync(cnt, 0, (size_t)NBINS * 4, stream);
  preph_kernel<<<7800, 256, 0, stream>>>(
      e1w, e2w, n1w, n2w, outw, e1b, n1b, rel_embs, role_embs, col_embs, dstI,
      wsd, e2p, n1p, n2p, outp, cnt, TR, TNp, TSp, TDp);
  scan_kernel<<<1, 1024, 0, stream>>>(cnt, cnt2);
  scat_kernel<<<3321, 256, 0, stream>>>(dstI, cnt, cnt2, perm, dstS);
  embed_kernel<<<HBLK, 256, 0, stream>>>(
      scalars, ncol, nrole, blk_col, blk_role, inw, inb,
      wsd, TSp, TDp, h, PS, PD);

  for (int l = 0; l < 3; ++l) {
    edge_kernel<<<NB, 256, 0, stream>>>(
        PS, PD, agg, bnd, perm, dstS, srcI, erel, TR + (size_t)l * 2048,
        e2p + (size_t)l * 65536, e2b + (size_t)l * 256);
    const int mode = (l < 2) ? 0 : 1;
    const int ln = (l + 1 < 3) ? l + 1 : 0;
    node_kernel<<<HBLK, 256, 0, stream>>>(
        h, agg, bnd, cnt2, nrole, ncol,
        n1p + (size_t)l * 131072, TNp + (size_t)l * 8192,
        n2p + (size_t)l * 65536,  n2b + (size_t)l * 256,
        lng + (size_t)l * 256, lnb + (size_t)l * 256,
        mode,
        wsd + (size_t)ln * 131072, TSp + (size_t)ln * 8192, TDp + (size_t)ln * 8192,
        PS, PD, outp, outb, (float*)d_out);
  }
}

// Round 10
// 1147.962 us; speedup vs baseline: 1.3895x; 1.0187x over previous
//
#include <hip/hip_runtime.h>

#define NN 50000
#define NE 800000
#define H 256
#define NB 12500            // edge blocks (64 edges each)
#define NBINS 50176         // NN padded
#define HBLK 782            // node blocks (64 nodes each)

typedef __bf16 bf16x8 __attribute__((ext_vector_type(8)));
typedef __bf16 bf16x4 __attribute__((ext_vector_type(4)));
typedef float f32x4 __attribute__((ext_vector_type(4)));

static __device__ __forceinline__ f32x4 mfma16(bf16x8 a, bf16x8 b, f32x4 c) {
  return __builtin_amdgcn_mfma_f32_16x16x32_bf16(a, b, c, 0, 0, 0);
}
static __device__ __forceinline__ bf16x8 bzero8() {
  bf16x8 z;
#pragma unroll
  for (int j = 0; j < 8; ++j) z[j] = (__bf16)0.f;
  return z;
}
static __device__ __forceinline__ float silu_f(float v) {
  return v * __builtin_amdgcn_rcpf(1.f + __builtin_amdgcn_exp2f(v * -1.442695041f));
}

// ---------------------------------------------------------------------------
// prep (blocks 0..4674) + hist (blocks 4675..7799).
// Repack fp32->bf16 [chunk][n][32k]; tables TRb (bf16 [8][256]) and
// TNp/TSp/TDp (bf16 [256][32] B-layout, k=role*3+col; TDp incl e1b, TNp n1b).
// cnt must be zeroed before this kernel (hist atomics).
// ---------------------------------------------------------------------------
__global__ void preph_kernel(
    const float* __restrict__ e1w, const float* __restrict__ e2w,
    const float* __restrict__ n1w, const float* __restrict__ n2w,
    const float* __restrict__ outw, const float* __restrict__ e1b,
    const float* __restrict__ n1b,
    const float* __restrict__ rel_embs, const float* __restrict__ role_embs,
    const float* __restrict__ col_embs, const int* __restrict__ dstI,
    __bf16* __restrict__ wsd, __bf16* __restrict__ e2p,
    __bf16* __restrict__ n1p, __bf16* __restrict__ n2p,
    __bf16* __restrict__ outp, int* __restrict__ cnt,
    __bf16* __restrict__ TRb, __bf16* __restrict__ TNp,
    __bf16* __restrict__ TSp, __bf16* __restrict__ TDp)
{
  if (blockIdx.x >= 4675) {
    const int e = (blockIdx.x - 4675) * 256 + threadIdx.x;
    if (e < NE) atomicAdd(&cnt[dstI[e]], 1);
    return;
  }
  int i = blockIdx.x * 256 + threadIdx.x;
  if (i < 3 * 131072) {
    const int l = i / 131072, rem = i % 131072;
    const int c = rem >> 14, r2 = rem & 16383;
    const int n = r2 >> 5, k = c * 32 + (r2 & 31);
    wsd[i] = (n < 256) ? (__bf16)e1w[((size_t)l * 560 + k) * 256 + n]
                       : (__bf16)e1w[((size_t)l * 560 + 256 + k) * 256 + (n - 256)];
    return;
  }
  i -= 3 * 131072;
  if (i < 3 * 65536) {
    const int l = i / 65536, rem = i % 65536;
    const int c = rem >> 13, r2 = rem & 8191;
    const int n = r2 >> 5, k = c * 32 + (r2 & 31);
    e2p[i] = (__bf16)e2w[((size_t)l * 256 + k) * 256 + n];
    return;
  }
  i -= 3 * 65536;
  if (i < 3 * 131072) {
    const int l = i / 131072, rem = i % 131072;
    const int c = rem >> 13, r2 = rem & 8191;
    const int n = r2 >> 5, k = c * 32 + (r2 & 31);   // k < 512
    n1p[i] = (__bf16)n1w[((size_t)l * 528 + k) * 256 + n];
    return;
  }
  i -= 3 * 131072;
  if (i < 3 * 65536) {
    const int l = i / 65536, rem = i % 65536;
    const int c = rem >> 13, r2 = rem & 8191;
    const int n = r2 >> 5, k = c * 32 + (r2 & 31);
    n2p[i] = (__bf16)n2w[((size_t)l * 256 + k) * 256 + n];
    return;
  }
  i -= 3 * 65536;
  if (i < 16384) {
    const int c = i >> 11, r2 = i & 2047;
    const int n = r2 >> 5, k = c * 32 + (r2 & 31);
    outp[i] = (__bf16)outw[(size_t)k * 64 + n];
    return;
  }
  i -= 16384;
  if (i < 768) {
    const int l = i >> 8, c = i & 255;
    float w[48];
#pragma unroll
    for (int j = 0; j < 48; ++j) w[j] = e1w[((size_t)l * 560 + 512 + j) * 256 + c];
#pragma unroll
    for (int r = 0; r < 8; ++r) {
      float s = 0.f;
#pragma unroll
      for (int j = 0; j < 16; ++j) s += rel_embs[l * 128 + r * 16 + j] * w[j];
      TRb[((size_t)l * 8 + r) * 256 + c] = (__bf16)s;
    }
    float wn[16];
#pragma unroll
    for (int j = 0; j < 16; ++j) wn[j] = n1w[((size_t)l * 528 + 512 + j) * 256 + c];
    const float bias = e1b[l * 256 + c];
    const float nbias = n1b[l * 256 + c];
    const size_t ob = ((size_t)l * 256 + c) * 32;
#pragma unroll
    for (int ro = 0; ro < 8; ++ro) {
      float ss = 0.f, sd = 0.f, sn = 0.f;
#pragma unroll
      for (int j = 0; j < 8; ++j) {
        const float re = role_embs[l * 64 + ro * 8 + j];
        ss += re * w[16 + j];
        sd += re * w[24 + j];
        sn += re * wn[j];
      }
#pragma unroll
      for (int co = 0; co < 3; ++co) {
        float cs = 0.f, cd = 0.f, cn = 0.f;
#pragma unroll
        for (int j = 0; j < 8; ++j) {
          const float ce = col_embs[l * 24 + co * 8 + j];
          cs += ce * w[32 + j];
          cd += ce * w[40 + j];
          cn += ce * wn[8 + j];
        }
        const int k = ro * 3 + co;
        TSp[ob + k] = (__bf16)(ss + cs);
        TDp[ob + k] = (__bf16)(sd + cd + bias);
        TNp[ob + k] = (__bf16)(sn + cn + nbias);
      }
    }
#pragma unroll
    for (int k = 24; k < 32; ++k) {
      TSp[ob + k] = (__bf16)0.f;
      TDp[ob + k] = (__bf16)0.f;
      TNp[ob + k] = (__bf16)0.f;
    }
  }
}

// ---------------------------------------------------------------------------
// Scan: cnt -> exclusive prefix (in place) + stable copy cnt2.
// ---------------------------------------------------------------------------
__global__ __launch_bounds__(1024) void scan_kernel(int* __restrict__ cnt,
                                                    int* __restrict__ cnt2) {
  __shared__ int wsum[16];
  __shared__ int carry;
  const int tid = threadIdx.x, lane = tid & 63, wid = tid >> 6;
  if (tid == 0) carry = 0;
  __syncthreads();
  for (int base = 0; base < NBINS; base += 4096) {
    const int idx = base + tid * 4;
    int4 v = make_int4(0, 0, 0, 0);
    if (idx < NBINS) v = *(const int4*)&cnt[idx];
    const int s1 = v.x + v.y, s2 = s1 + v.z, tot = s2 + v.w;
    int x = tot;
#pragma unroll
    for (int d = 1; d < 64; d <<= 1) {
      const int y = __shfl_up(x, d, 64);
      if (lane >= d) x += y;
    }
    if (lane == 63) wsum[wid] = x;
    __syncthreads();
    int wpref = 0;
#pragma unroll
    for (int w = 0; w < 16; ++w)
      if (w < wid) wpref += wsum[w];
    const int ex = carry + wpref + (x - tot);
    if (idx < NBINS) {
      int4 o;
      o.x = ex; o.y = ex + v.x; o.z = ex + s1; o.w = ex + s2;
      *(int4*)&cnt[idx] = o;
      *(int4*)&cnt2[idx] = o;
    }
    __syncthreads();
    if (tid == 0) {
      int s = 0;
#pragma unroll
      for (int w = 0; w < 16; ++w) s += wsum[w];
      carry += s;
    }
    __syncthreads();
  }
}

// ---------------------------------------------------------------------------
// scem: payload scatter (blocks 0..3124) + dstS run-fill (3125..3320) +
// embed h = [scalars,color,role]@in_w + in_b (3321..4102, coalesced store).
// ---------------------------------------------------------------------------
__global__ __launch_bounds__(256, 4) void scem_kernel(
    const int* __restrict__ srcI, const int* __restrict__ dstI,
    const int* __restrict__ erel, int* __restrict__ cnt,
    const int* __restrict__ cnt2,
    int* __restrict__ esr, int* __restrict__ dstS,
    const float* __restrict__ scalars, const int* __restrict__ ncol,
    const int* __restrict__ nrole,
    const float* __restrict__ colEmb, const float* __restrict__ roleEmb,
    const float* __restrict__ inw, const float* __restrict__ inb,
    __bf16* __restrict__ h)
{
  if (blockIdx.x < 3125) {
    const int e = blockIdx.x * 256 + threadIdx.x;
    if (e < NE) {
      const int pos = atomicAdd(&cnt[dstI[e]], 1);
      esr[pos] = srcI[e] | (erel[e] << 16);
    }
    return;
  }
  if (blockIdx.x < 3321) {
    const int n = (blockIdx.x - 3125) * 256 + threadIdx.x;
    if (n < NN) {
      const int st = cnt2[n], en = cnt2[n + 1];
      for (int p = st; p < en; ++p) dstS[p] = n;
    }
    return;
  }
  __shared__ __align__(16) char uni[33792];
  auto Ain = (__bf16 (*)[40])uni;    // [64][40] input features
  auto Hs  = (__bf16 (*)[264])uni;   // [64][264] h tile (aliased)

  const int tid  = threadIdx.x;
  const int lane = tid & 63;
  const int wave = tid >> 6;
  const int l15  = lane & 15;
  const int quad = lane >> 4;
  const int n0   = (blockIdx.x - 3321) * 64;
  const int colW = wave * 64;
  const int rowS = tid >> 5, colS = (tid & 31) * 8;

  {
    const int row = tid >> 2, q = tid & 3;
    const int n = n0 + row;
    __bf16* dp = &Ain[row][q * 8];
    if (n < NN) {
      if (q < 2) {
#pragma unroll
        for (int j = 0; j < 8; ++j) dp[j] = (__bf16)scalars[(size_t)n * 16 + q * 8 + j];
      } else if (q == 2) {
        const int c = ncol[n];
#pragma unroll
        for (int j = 0; j < 8; ++j) dp[j] = (__bf16)colEmb[c * 8 + j];
      } else {
        const int r = nrole[n];
#pragma unroll
        for (int j = 0; j < 8; ++j) dp[j] = (__bf16)roleEmb[r * 8 + j];
      }
    } else {
#pragma unroll
      for (int j = 0; j < 8; ++j) dp[j] = (__bf16)0.f;
    }
  }
  __syncthreads();

  f32x4 acc[4][4] = {};
  {
    bf16x8 bfr[4], afr[4];
#pragma unroll
    for (int nj = 0; nj < 4; ++nj) {
      const int col = colW + nj * 16 + l15;
#pragma unroll
      for (int j = 0; j < 8; ++j) bfr[nj][j] = (__bf16)inw[(quad * 8 + j) * 256 + col];
    }
#pragma unroll
    for (int mi = 0; mi < 4; ++mi)
      afr[mi] = *(const bf16x8*)&Ain[mi * 16 + l15][quad * 8];
#pragma unroll
    for (int mi = 0; mi < 4; ++mi)
#pragma unroll
      for (int nj = 0; nj < 4; ++nj)
        acc[mi][nj] = mfma16(afr[mi], bfr[nj], acc[mi][nj]);
  }
  float bi[4];
#pragma unroll
  for (int nj = 0; nj < 4; ++nj) bi[nj] = inb[colW + nj * 16 + l15];
  __syncthreads();   // Ain reads done before Hs (aliased) write

#pragma unroll
  for (int mi = 0; mi < 4; ++mi)
#pragma unroll
    for (int r = 0; r < 4; ++r) {
      const int row = mi * 16 + quad * 4 + r;
#pragma unroll
      for (int nj = 0; nj < 4; ++nj)
        Hs[row][colW + nj * 16 + l15] = (__bf16)(acc[mi][nj][r] + bi[nj]);
    }
  __syncthreads();
#pragma unroll
  for (int it = 0; it < 8; ++it) {
    const int row = it * 8 + rowS;
    const int n = n0 + row;
    if (n < NN)
      *(bf16x8*)(h + (size_t)n * H + colS) = *(const bf16x8*)&Hs[row][colS];
  }
}

// ---------------------------------------------------------------------------
// pre: P = h @ (Ws|Wd) + T[role,col] (one half per block), streaming GEMM.
// blockIdx: ng = >>1, hf = &1. Coalesced load h, coalesced store P.
// ---------------------------------------------------------------------------
__global__ __launch_bounds__(256, 4) void pre_kernel(
    const __bf16* __restrict__ h, const int* __restrict__ nrole,
    const int* __restrict__ ncol, const __bf16* __restrict__ wsd,
    const __bf16* __restrict__ TSp, const __bf16* __restrict__ TDp,
    __bf16* __restrict__ PS, __bf16* __restrict__ PD)
{
  __shared__ __align__(16) __bf16 Hs[64][296];
  __shared__ int sTi[64];

  const int tid  = threadIdx.x;
  const int lane = tid & 63;
  const int wave = tid >> 6;
  const int l15  = lane & 15;
  const int quad = lane >> 4;
  const int ng   = blockIdx.x >> 1;
  const int hf   = blockIdx.x & 1;
  const int n0   = ng * 64;
  const int colW = wave * 64;
  const int rowS = tid >> 5, colS = (tid & 31) * 8;

  if (tid < 64) {
    const int n = n0 + tid;
    sTi[tid] = (n < NN) ? (nrole[n] * 3 + ncol[n]) : 0;
  }
#pragma unroll
  for (int it = 0; it < 8; ++it) {
    const int row = it * 8 + rowS;
    const int n = n0 + row;
    bf16x8 v = bzero8();
    if (n < NN) v = *(const bf16x8*)(h + (size_t)n * H + colS);
    *(bf16x8*)&Hs[row][colS] = v;
  }
  __syncthreads();
  {
    const int row = tid >> 2, q = tid & 3;
    const int ti = sTi[row];
    bf16x8 v;
#pragma unroll
    for (int j = 0; j < 8; ++j) v[j] = (__bf16)((q * 8 + j == ti) ? 1.f : 0.f);
    *(bf16x8*)&Hs[row][256 + q * 8] = v;
  }
  __syncthreads();

  f32x4 ap[4][4] = {};
#pragma unroll
  for (int c = 0; c < 9; ++c) {
    const __bf16* bp = (c < 8) ? wsd + ((size_t)c * 512 + hf * 256) * 32
                               : (hf ? TDp : TSp);
    bf16x8 bfr[4], afr[4];
#pragma unroll
    for (int nj = 0; nj < 4; ++nj)
      bfr[nj] = *(const bf16x8*)(bp + ((size_t)(colW + nj * 16 + l15)) * 32 + quad * 8);
#pragma unroll
    for (int mi = 0; mi < 4; ++mi)
      afr[mi] = *(const bf16x8*)&Hs[mi * 16 + l15][c * 32 + quad * 8];
#pragma unroll
    for (int mi = 0; mi < 4; ++mi)
#pragma unroll
      for (int nj = 0; nj < 4; ++nj)
        ap[mi][nj] = mfma16(afr[mi], bfr[nj], ap[mi][nj]);
  }
  __syncthreads();   // Hs reads done

#pragma unroll
  for (int mi = 0; mi < 4; ++mi)
#pragma unroll
    for (int r = 0; r < 4; ++r) {
      const int row = mi * 16 + quad * 4 + r;
#pragma unroll
      for (int nj = 0; nj < 4; ++nj)
        Hs[row][colW + nj * 16 + l15] = (__bf16)ap[mi][nj][r];
    }
  __syncthreads();
  __bf16* P = hf ? PD : PS;
#pragma unroll
  for (int it = 0; it < 8; ++it) {
    const int row = it * 8 + rowS;
    const int n = n0 + row;
    if (n < NN)
      *(bf16x8*)(P + (size_t)n * H + colS) = *(const bf16x8*)&Hs[row][colS];
  }
}

// ---------------------------------------------------------------------------
// Fused edge MLP + segmented scatter (sorted by dst, no atomics).
// ---------------------------------------------------------------------------
__global__ __launch_bounds__(256, 4) void edge_kernel(
    const __bf16* __restrict__ PS, const __bf16* __restrict__ PD,
    __bf16* __restrict__ agg, __bf16* __restrict__ bnd,
    const int* __restrict__ esr, const int* __restrict__ dstS,
    const __bf16* __restrict__ TRb,
    const __bf16* __restrict__ e2p, const float* __restrict__ e2b)
{
  __shared__ __align__(16) char uni[34816];
  __shared__ __bf16 sTrel[8][256];
  __shared__ int sSrc[64], sDst[64], sRel[64];

  auto A2  = (__bf16 (*)[264])uni;      // [64][264]  m1 row-major
  auto A2t = (__bf16 (*)[68])uni;       // [256][68]  m2 col-major (aliased)

  const int tid  = threadIdx.x;
  const int lane = tid & 63;
  const int wave = tid >> 6;
  const int l15  = lane & 15;
  const int quad = lane >> 4;
  const int e0   = blockIdx.x * 64;
  const int colW = wave * 64;

  if (tid < 64) {
    const int u = esr[e0 + tid];
    sSrc[tid] = u & 0xffff;
    sRel[tid] = u >> 16;
    sDst[tid] = dstS[e0 + tid];
  }
  {
    const int r = tid >> 5, cs = (tid & 31) * 8;
    *(bf16x8*)&sTrel[r][cs] = *(const bf16x8*)(TRb + r * 256 + cs);
  }
  __syncthreads();

  // ---- m1 ----
  {
    const int brow = tid >> 5;
    const int cs = (tid & 31) * 8;
#pragma unroll
    for (int it = 0; it < 8; ++it) {
      const int row = it * 8 + brow;
      const bf16x8 a = *(const bf16x8*)(PS + (size_t)sSrc[row] * H + cs);
      const bf16x8 b = *(const bf16x8*)(PD + (size_t)sDst[row] * H + cs);
      const bf16x8 t = *(const bf16x8*)&sTrel[sRel[row]][cs];
      bf16x8 o;
#pragma unroll
      for (int j = 0; j < 8; ++j)
        o[j] = (__bf16)silu_f((float)a[j] + (float)b[j] + (float)t[j]);
      *(bf16x8*)&A2[row][cs] = o;
    }
  }
  __syncthreads();

  // ---- GEMM2 ----
  f32x4 acc2[4][4] = {};
#pragma unroll
  for (int c = 0; c < 8; ++c) {
    bf16x8 bfr[4], afr[4];
#pragma unroll
    for (int nj = 0; nj < 4; ++nj)
      bfr[nj] = *(const bf16x8*)(e2p + ((size_t)c * 256 + colW + nj * 16 + l15) * 32 + quad * 8);
#pragma unroll
    for (int mi = 0; mi < 4; ++mi)
      afr[mi] = *(const bf16x8*)&A2[mi * 16 + l15][c * 32 + quad * 8];
#pragma unroll
    for (int mi = 0; mi < 4; ++mi)
#pragma unroll
      for (int nj = 0; nj < 4; ++nj)
        acc2[mi][nj] = mfma16(afr[mi], bfr[nj], acc2[mi][nj]);
  }

  float b2[4];
#pragma unroll
  for (int nj = 0; nj < 4; ++nj) b2[nj] = e2b[colW + nj * 16 + l15];
  __syncthreads();   // A2 reads done before A2t (aliased) write

#pragma unroll
  for (int mi = 0; mi < 4; ++mi)
#pragma unroll
    for (int nj = 0; nj < 4; ++nj) {
      const int col = colW + nj * 16 + l15;
      bf16x4 pv;
#pragma unroll
      for (int r = 0; r < 4; ++r)
        pv[r] = (__bf16)silu_f(acc2[mi][nj][r] + b2[nj]);
      *(bf16x4*)&A2t[col][mi * 16 + quad * 4] = pv;
    }
  __syncthreads();

  // ---- segmented reduce: thread = column; all plain stores (bf16) ----
  {
    const int col = tid;
    const bool f = (lane > 0) && (sDst[lane] != sDst[lane - 1]);
    const unsigned long long mask = __ballot(f);
    bf16x4 v[16];
#pragma unroll
    for (int j = 0; j < 16; ++j) v[j] = *(const bf16x4*)&A2t[col][j * 4];
    __bf16* bnd0 = bnd + ((size_t)2 * blockIdx.x) * 256 + col;
    float sum = 0.f;
    int s0 = 0;
#pragma unroll
    for (int r = 0; r < 64; ++r) {
      sum += (float)v[r >> 2][r & 3];
      if (r == 63 || ((mask >> (r + 1)) & 1ull)) {
        const bool isFirst = (s0 == 0), isLast = (r == 63);
        if (isFirst) {
          bnd0[0] = (__bf16)(isLast ? 0.f : sum);
          if (isLast) bnd0[256] = (__bf16)sum;
        } else if (isLast) {
          bnd0[256] = (__bf16)sum;
        } else {
          agg[(size_t)sDst[r] * H + col] = (__bf16)sum;
        }
        sum = 0.f;
        s0 = r + 1;
      }
    }
  }
}

// ---------------------------------------------------------------------------
// node core: GEMM1 (16 h/agg chunks + onehot TNp chunk) -> silu -> GEMM2 ->
// residual (LDS restage of old h) -> LayerNorm -> h_new (mode 0) or out (1).
// No P-GEMM, no acch: low VGPR -> 4 blocks/CU.
// ---------------------------------------------------------------------------
__global__ __launch_bounds__(256, 4) void node_kernel(
    __bf16* __restrict__ h, const __bf16* __restrict__ agg,
    const __bf16* __restrict__ bnd, const int* __restrict__ cnt2,
    const int* __restrict__ nrole, const int* __restrict__ ncol,
    const __bf16* __restrict__ n1p, const __bf16* __restrict__ TNp,
    const __bf16* __restrict__ n2p, const float* __restrict__ n2b,
    const float* __restrict__ lng, const float* __restrict__ lnb,
    const int mode,
    const __bf16* __restrict__ outp, const float* __restrict__ outb,
    float* __restrict__ out)
{
  __shared__ __align__(16) char uni[33792];
  __shared__ float sSum[64][4], sSsq[64][4];
  __shared__ int sTi[64], sPcnt[64], sPidx[64][4];

  auto Abuf = (__bf16 (*)[72])uni;   // [64][72]   GEMM1 staging
  auto A2   = (__bf16 (*)[264])uni;  // [64][264]  GEMM1 out / old-h / h_new

  const int tid  = threadIdx.x;
  const int lane = tid & 63;
  const int wave = tid >> 6;
  const int l15  = lane & 15;
  const int quad = lane >> 4;
  const int n0   = blockIdx.x * 64;
  const int colW = wave * 64;
  const int rowS = tid >> 5, colS = (tid & 31) * 8;

  if (tid < 64) {
    const int n = n0 + tid;
    int st = 0, en = 0, ti = 0;
    if (n < NN) {
      st = cnt2[n];
      en = cnt2[n + 1];
      ti = nrole[n] * 3 + ncol[n];
    }
    sTi[tid] = ti;
    int pc = 0, pidx[4] = {0, 0, 0, 0};
    if (en > st) {
      const int bs = st >> 6, be = (en - 1) >> 6;
      if (bs == be && (st & 63) != 0 && (en & 63) != 0) {
        pc = -1;                       // strictly interior: read agg row
      } else {
        for (int b = bs; b <= be && pc < 4; ++b) {
          if (b > bs || (st & 63) == 0) pidx[pc++] = 2 * b;
          if ((b < be || (en & 63) == 0) && pc < 4) pidx[pc++] = 2 * b + 1;
        }
      }
    }
    sPcnt[tid] = pc;
#pragma unroll
    for (int j = 0; j < 4; ++j) sPidx[tid][j] = pidx[j];
  }
  __syncthreads();

  f32x4 acc[4][4] = {};
  for (int s = 0; s < 8; ++s) {
    if (s) __syncthreads();
    if (s < 4) {
#pragma unroll
      for (int it = 0; it < 2; ++it) {
        const int t = tid + it * 256;
        const int row = t >> 3, seg = t & 7;
        const int n = n0 + row;
        bf16x8 v = bzero8();
        if (n < NN) v = *(const bf16x8*)(h + (size_t)n * H + s * 64 + seg * 8);
        *(bf16x8*)&Abuf[row][seg * 8] = v;
      }
    } else {
#pragma unroll
      for (int it = 0; it < 2; ++it) {
        const int t = tid + it * 256;
        const int row = t >> 3, seg = t & 7;
        const int off = (s - 4) * 64 + seg * 8;
        const int pc = sPcnt[row];
        bf16x8 v = bzero8();
        if (pc == -1) {
          v = *(const bf16x8*)(agg + (size_t)(n0 + row) * H + off);
        } else if (pc > 0) {
          float a8[8] = {0.f, 0.f, 0.f, 0.f, 0.f, 0.f, 0.f, 0.f};
          for (int j = 0; j < pc; ++j) {
            const bf16x8 pv = *(const bf16x8*)(bnd + (size_t)sPidx[row][j] * 256 + off);
#pragma unroll
            for (int k = 0; k < 8; ++k) a8[k] += (float)pv[k];
          }
#pragma unroll
          for (int k = 0; k < 8; ++k) v[k] = (__bf16)a8[k];
        }
        *(bf16x8*)&Abuf[row][seg * 8] = v;
      }
    }
    __syncthreads();
#pragma unroll
    for (int cc = 0; cc < 2; ++cc) {
      const int c = 2 * s + cc;
      bf16x8 bfr[4], afr[4];
#pragma unroll
      for (int nj = 0; nj < 4; ++nj)
        bfr[nj] = *(const bf16x8*)(n1p + ((size_t)c * 256 + colW + nj * 16 + l15) * 32 + quad * 8);
#pragma unroll
      for (int mi = 0; mi < 4; ++mi)
        afr[mi] = *(const bf16x8*)&Abuf[mi * 16 + l15][cc * 32 + quad * 8];
#pragma unroll
      for (int mi = 0; mi < 4; ++mi)
#pragma unroll
        for (int nj = 0; nj < 4; ++nj)
          acc[mi][nj] = mfma16(afr[mi], bfr[nj], acc[mi][nj]);
    }
  }
  // onehot stage -> chunk 16 (TNp table add, includes n1b)
  __syncthreads();
  {
    const int row = tid >> 2, q = tid & 3;
    const int ti = sTi[row];
    bf16x8 v;
#pragma unroll
    for (int j = 0; j < 8; ++j) v[j] = (__bf16)((q * 8 + j == ti) ? 1.f : 0.f);
    *(bf16x8*)&Abuf[row][q * 8] = v;
  }
  __syncthreads();
  {
    bf16x8 bfr[4], afr[4];
#pragma unroll
    for (int nj = 0; nj < 4; ++nj)
      bfr[nj] = *(const bf16x8*)(TNp + ((size_t)(colW + nj * 16 + l15)) * 32 + quad * 8);
#pragma unroll
    for (int mi = 0; mi < 4; ++mi)
      afr[mi] = *(const bf16x8*)&Abuf[mi * 16 + l15][quad * 8];
#pragma unroll
    for (int mi = 0; mi < 4; ++mi)
#pragma unroll
      for (int nj = 0; nj < 4; ++nj)
        acc[mi][nj] = mfma16(afr[mi], bfr[nj], acc[mi][nj]);
  }
  __syncthreads();   // Abuf reads done before A2 (aliased) write

  // GEMM1 epilogue: silu -> A2
#pragma unroll
  for (int mi = 0; mi < 4; ++mi)
#pragma unroll
    for (int r = 0; r < 4; ++r) {
      const int row = mi * 16 + quad * 4 + r;
#pragma unroll
      for (int nj = 0; nj < 4; ++nj)
        A2[row][colW + nj * 16 + l15] = (__bf16)silu_f(acc[mi][nj][r]);
    }
  __syncthreads();

  f32x4 acc2[4][4] = {};
#pragma unroll
  for (int c = 0; c < 8; ++c) {
    bf16x8 bfr[4], afr[4];
#pragma unroll
    for (int nj = 0; nj < 4; ++nj)
      bfr[nj] = *(const bf16x8*)(n2p + ((size_t)c * 256 + colW + nj * 16 + l15) * 32 + quad * 8);
#pragma unroll
    for (int mi = 0; mi < 4; ++mi)
      afr[mi] = *(const bf16x8*)&A2[mi * 16 + l15][c * 32 + quad * 8];
#pragma unroll
    for (int mi = 0; mi < 4; ++mi)
#pragma unroll
      for (int nj = 0; nj < 4; ++nj)
        acc2[mi][nj] = mfma16(afr[mi], bfr[nj], acc2[mi][nj]);
  }
  __syncthreads();   // A2 (silu vals) reads done

  // restage old h into A2 for the residual
#pragma unroll
  for (int it = 0; it < 8; ++it) {
    const int row = it * 8 + rowS;
    const int n = n0 + row;
    bf16x8 v = bzero8();
    if (n < NN) v = *(const bf16x8*)(h + (size_t)n * H + colS);
    *(bf16x8*)&A2[row][colS] = v;
  }
  __syncthreads();

  float b2[4], g4[4], bb4[4];
#pragma unroll
  for (int nj = 0; nj < 4; ++nj) {
    const int col = colW + nj * 16 + l15;
    b2[nj] = n2b[col]; g4[nj] = lng[col]; bb4[nj] = lnb[col];
  }
#pragma unroll
  for (int mi = 0; mi < 4; ++mi)
#pragma unroll
    for (int nj = 0; nj < 4; ++nj) {
      const int col = colW + nj * 16 + l15;
#pragma unroll
      for (int r = 0; r < 4; ++r)
        acc2[mi][nj][r] += b2[nj] + (float)A2[mi * 16 + quad * 4 + r][col];
    }

#pragma unroll
  for (int mi = 0; mi < 4; ++mi)
#pragma unroll
    for (int r = 0; r < 4; ++r) {
      float s1 = 0.f, s2 = 0.f;
#pragma unroll
      for (int nj = 0; nj < 4; ++nj) {
        const float v = acc2[mi][nj][r];
        s1 += v; s2 += v * v;
      }
#pragma unroll
      for (int d = 1; d < 16; d <<= 1) {
        s1 += __shfl_xor(s1, d, 16);
        s2 += __shfl_xor(s2, d, 16);
      }
      if (l15 == 0) {
        const int row = mi * 16 + quad * 4 + r;
        sSum[row][wave] = s1; sSsq[row][wave] = s2;
      }
    }
  __syncthreads();   // all residual reads of A2 complete; stats visible

#pragma unroll
  for (int mi = 0; mi < 4; ++mi)
#pragma unroll
    for (int r = 0; r < 4; ++r) {
      const int row = mi * 16 + quad * 4 + r;
      const float t1 = sSum[row][0] + sSum[row][1] + sSum[row][2] + sSum[row][3];
      const float t2 = sSsq[row][0] + sSsq[row][1] + sSsq[row][2] + sSsq[row][3];
      const float mu = t1 * (1.f / 256.f);
      float var = t2 * (1.f / 256.f) - mu * mu;
      var = var < 0.f ? 0.f : var;
      const float rstd = rsqrtf(var + 1e-5f);
#pragma unroll
      for (int nj = 0; nj < 4; ++nj) {
        const int col = colW + nj * 16 + l15;
        const float o = g4[nj] * (acc2[mi][nj][r] - mu) * rstd + bb4[nj];
        A2[row][col] = (__bf16)o;
      }
    }
  __syncthreads();   // h_new staged in A2

  if (mode == 0) {
#pragma unroll
    for (int it = 0; it < 8; ++it) {
      const int row = it * 8 + rowS;
      const int n = n0 + row;
      if (n < NN)
        *(bf16x8*)(h + (size_t)n * H + colS) = *(const bf16x8*)&A2[row][colS];
    }
  } else {
    f32x4 ao[4] = {};
#pragma unroll
    for (int c = 0; c < 8; ++c) {
      const bf16x8 bfr = *(const bf16x8*)(outp + ((size_t)c * 64 + wave * 16 + l15) * 32 + quad * 8);
#pragma unroll
      for (int mi = 0; mi < 4; ++mi) {
        const bf16x8 afr = *(const bf16x8*)&A2[mi * 16 + l15][c * 32 + quad * 8];
        ao[mi] = mfma16(afr, bfr, ao[mi]);
      }
    }
    const float ob = outb[wave * 16 + l15];
#pragma unroll
    for (int mi = 0; mi < 4; ++mi)
#pragma unroll
      for (int r = 0; r < 4; ++r) {
        const int n = n0 + mi * 16 + quad * 4 + r;
        if (n < NN) out[(size_t)n * 64 + wave * 16 + l15] = ao[mi][r] + ob;
      }
  }
}

// ---------------------------------------------------------------------------
extern "C" void kernel_launch(void* const* d_in, const int* in_sizes, int n_in,
                              void* d_out, int out_size, void* d_ws, size_t ws_size,
                              hipStream_t stream) {
  const float* scalars   = (const float*)d_in[0];
  const int*   ei        = (const int*)d_in[1];
  const int*   erel      = (const int*)d_in[2];
  const int*   ncol      = (const int*)d_in[3];
  const int*   nrole     = (const int*)d_in[4];
  const float* blk_role  = (const float*)d_in[5];
  const float* blk_col   = (const float*)d_in[6];
  const float* inw       = (const float*)d_in[7];
  const float* inb       = (const float*)d_in[8];
  const float* rel_embs  = (const float*)d_in[9];
  const float* role_embs = (const float*)d_in[10];
  const float* col_embs  = (const float*)d_in[11];
  const float* e1w       = (const float*)d_in[12];
  const float* e1b       = (const float*)d_in[13];
  const float* e2w       = (const float*)d_in[14];
  const float* e2b       = (const float*)d_in[15];
  const float* n1w       = (const float*)d_in[16];
  const float* n1b       = (const float*)d_in[17];
  const float* n2w       = (const float*)d_in[18];
  const float* n2b       = (const float*)d_in[19];
  const float* lng       = (const float*)d_in[20];
  const float* lnb       = (const float*)d_in[21];
  const float* outw      = (const float*)d_in[22];
  const float* outb      = (const float*)d_in[23];

  const int* srcI = ei;
  const int* dstI = ei + NE;

  char* ws = (char*)d_ws;
  size_t off = 0;
  auto take = [&](size_t bytes) -> char* {
    off = (off + 255) & ~(size_t)255;
    char* p = ws + off;
    off += bytes;
    return p;
  };
  __bf16* h    = (__bf16*)take((size_t)NN * H * 2);
  __bf16* agg  = (__bf16*)take((size_t)NN * H * 2);
  __bf16* bnd  = (__bf16*)take((size_t)2 * NB * 256 * 2);
  __bf16* PS   = (__bf16*)take((size_t)NN * H * 2);
  __bf16* PD   = (__bf16*)take((size_t)NN * H * 2);
  __bf16* wsd  = (__bf16*)take((size_t)3 * 131072 * 2);
  __bf16* e2p  = (__bf16*)take((size_t)3 * 65536 * 2);
  __bf16* n1p  = (__bf16*)take((size_t)3 * 131072 * 2);
  __bf16* n2p  = (__bf16*)take((size_t)3 * 65536 * 2);
  __bf16* outp = (__bf16*)take((size_t)16384 * 2);
  __bf16* TRb  = (__bf16*)take((size_t)3 * 8 * 256 * 2);
  __bf16* TNp  = (__bf16*)take((size_t)3 * 8192 * 2);
  __bf16* TSp  = (__bf16*)take((size_t)3 * 8192 * 2);
  __bf16* TDp  = (__bf16*)take((size_t)3 * 8192 * 2);
  int*    cnt  = (int*)take((size_t)NBINS * 4);
  int*    cnt2 = (int*)take((size_t)NBINS * 4);
  int*    esr  = (int*)take((size_t)NE * 4);
  int*    dstS = (int*)take((size_t)NE * 4);

  hipMemsetAsync(cnt, 0, (size_t)NBINS * 4, stream);
  preph_kernel<<<7800, 256, 0, stream>>>(
      e1w, e2w, n1w, n2w, outw, e1b, n1b, rel_embs, role_embs, col_embs, dstI,
      wsd, e2p, n1p, n2p, outp, cnt, TRb, TNp, TSp, TDp);
  scan_kernel<<<1, 1024, 0, stream>>>(cnt, cnt2);
  scem_kernel<<<4103, 256, 0, stream>>>(
      srcI, dstI, erel, cnt, cnt2, esr, dstS,
      scalars, ncol, nrole, blk_col, blk_role, inw, inb, h);
  pre_kernel<<<2 * HBLK, 256, 0, stream>>>(
      h, nrole, ncol, wsd, TSp, TDp, PS, PD);

  for (int l = 0; l < 3; ++l) {
    edge_kernel<<<NB, 256, 0, stream>>>(
        PS, PD, agg, bnd, esr, dstS, TRb + (size_t)l * 2048,
        e2p + (size_t)l * 65536, e2b + (size_t)l * 256);
    const int mode = (l < 2) ? 0 : 1;
    node_kernel<<<HBLK, 256, 0, stream>>>(
        h, agg, bnd, cnt2, nrole, ncol,
        n1p + (size_t)l * 131072, TNp + (size_t)l * 8192,
        n2p + (size_t)l * 65536,  n2b + (size_t)l * 256,
        lng + (size_t)l * 256, lnb + (size_t)l * 256,
        mode, outp, outb, (float*)d_out);
    if (l < 2) {
      const int ln = l + 1;
      pre_kernel<<<2 * HBLK, 256, 0, stream>>>(
          h, nrole, ncol, wsd + (size_t)ln * 131072,
          TSp + (size_t)ln * 8192, TDp + (size_t)ln * 8192, PS, PD);
    }
  }
}

// Round 11
// 1112.849 us; speedup vs baseline: 1.4333x; 1.0316x over previous
//
#include <hip/hip_runtime.h>
#include <hip/hip_fp16.h>

#define NN 50000
#define NE 800000
#define H 256
#define NB 12500            // edge blocks (64 edges each)
#define NBINS 50176         // NN padded
#define HBLK 782            // node blocks (64 nodes each)

typedef __bf16 bf16x8 __attribute__((ext_vector_type(8)));
typedef __bf16 bf16x4 __attribute__((ext_vector_type(4)));
typedef _Float16 f16x8 __attribute__((ext_vector_type(8)));
typedef float f32x4 __attribute__((ext_vector_type(4)));

struct h8 { __half2 h[4]; };   // 16B: 8 halves
struct h4 { __half e[4]; };    // 8B: 4 halves

static __device__ __forceinline__ f32x4 mfma16(bf16x8 a, bf16x8 b, f32x4 c) {
  return __builtin_amdgcn_mfma_f32_16x16x32_bf16(a, b, c, 0, 0, 0);
}
static __device__ __forceinline__ f32x4 mfma16h(f16x8 a, f16x8 b, f32x4 c) {
  return __builtin_amdgcn_mfma_f32_16x16x32_f16(a, b, c, 0, 0, 0);
}
static __device__ __forceinline__ bf16x8 bzero8() {
  bf16x8 z;
#pragma unroll
  for (int j = 0; j < 8; ++j) z[j] = (__bf16)0.f;
  return z;
}
static __device__ __forceinline__ float silu_f(float v) {
  return v * __builtin_amdgcn_rcpf(1.f + __builtin_amdgcn_exp2f(v * -1.442695041f));
}
// packed f16 silu: x * rcp(1 + 2^(-x*log2e))
static __device__ __forceinline__ __half2 silu2(__half2 x) {
  const __half2 k = __float2half2_rn(-1.4426950408889634f);
  const __half2 one = __float2half2_rn(1.0f);
  const __half2 e = h2exp2(__hmul2(x, k));
  return __hmul2(x, h2rcp(__hadd2(one, e)));
}

// ---------------------------------------------------------------------------
// prep (blocks 0..4674) + hist (blocks 4675..7799).
// Repack weights [chunk][n][32k]: wsd/n1p/n2p bf16; e2p f16 (edge GEMM2).
// Tables: TRb f16 [8][256]; TNp/TSp/TDp bf16 [256][32] B-layout.
// cnt must be zeroed before this kernel (hist atomics).
// ---------------------------------------------------------------------------
__global__ void preph_kernel(
    const float* __restrict__ e1w, const float* __restrict__ e2w,
    const float* __restrict__ n1w, const float* __restrict__ n2w,
    const float* __restrict__ outw, const float* __restrict__ e1b,
    const float* __restrict__ n1b,
    const float* __restrict__ rel_embs, const float* __restrict__ role_embs,
    const float* __restrict__ col_embs, const int* __restrict__ dstI,
    __bf16* __restrict__ wsd, __half* __restrict__ e2p,
    __bf16* __restrict__ n1p, __bf16* __restrict__ n2p,
    __bf16* __restrict__ outp, int* __restrict__ cnt,
    __half* __restrict__ TRb, __bf16* __restrict__ TNp,
    __bf16* __restrict__ TSp, __bf16* __restrict__ TDp)
{
  if (blockIdx.x >= 4675) {
    const int e = (blockIdx.x - 4675) * 256 + threadIdx.x;
    if (e < NE) atomicAdd(&cnt[dstI[e]], 1);
    return;
  }
  int i = blockIdx.x * 256 + threadIdx.x;
  if (i < 3 * 131072) {
    const int l = i / 131072, rem = i % 131072;
    const int c = rem >> 14, r2 = rem & 16383;
    const int n = r2 >> 5, k = c * 32 + (r2 & 31);
    wsd[i] = (n < 256) ? (__bf16)e1w[((size_t)l * 560 + k) * 256 + n]
                       : (__bf16)e1w[((size_t)l * 560 + 256 + k) * 256 + (n - 256)];
    return;
  }
  i -= 3 * 131072;
  if (i < 3 * 65536) {
    const int l = i / 65536, rem = i % 65536;
    const int c = rem >> 13, r2 = rem & 8191;
    const int n = r2 >> 5, k = c * 32 + (r2 & 31);
    e2p[i] = __float2half(e2w[((size_t)l * 256 + k) * 256 + n]);
    return;
  }
  i -= 3 * 65536;
  if (i < 3 * 131072) {
    const int l = i / 131072, rem = i % 131072;
    const int c = rem >> 13, r2 = rem & 8191;
    const int n = r2 >> 5, k = c * 32 + (r2 & 31);   // k < 512
    n1p[i] = (__bf16)n1w[((size_t)l * 528 + k) * 256 + n];
    return;
  }
  i -= 3 * 131072;
  if (i < 3 * 65536) {
    const int l = i / 65536, rem = i % 65536;
    const int c = rem >> 13, r2 = rem & 8191;
    const int n = r2 >> 5, k = c * 32 + (r2 & 31);
    n2p[i] = (__bf16)n2w[((size_t)l * 256 + k) * 256 + n];
    return;
  }
  i -= 3 * 65536;
  if (i < 16384) {
    const int c = i >> 11, r2 = i & 2047;
    const int n = r2 >> 5, k = c * 32 + (r2 & 31);
    outp[i] = (__bf16)outw[(size_t)k * 64 + n];
    return;
  }
  i -= 16384;
  if (i < 768) {
    const int l = i >> 8, c = i & 255;
    float w[48];
#pragma unroll
    for (int j = 0; j < 48; ++j) w[j] = e1w[((size_t)l * 560 + 512 + j) * 256 + c];
#pragma unroll
    for (int r = 0; r < 8; ++r) {
      float s = 0.f;
#pragma unroll
      for (int j = 0; j < 16; ++j) s += rel_embs[l * 128 + r * 16 + j] * w[j];
      TRb[((size_t)l * 8 + r) * 256 + c] = __float2half(s);
    }
    float wn[16];
#pragma unroll
    for (int j = 0; j < 16; ++j) wn[j] = n1w[((size_t)l * 528 + 512 + j) * 256 + c];
    const float bias = e1b[l * 256 + c];
    const float nbias = n1b[l * 256 + c];
    const size_t ob = ((size_t)l * 256 + c) * 32;
#pragma unroll
    for (int ro = 0; ro < 8; ++ro) {
      float ss = 0.f, sd = 0.f, sn = 0.f;
#pragma unroll
      for (int j = 0; j < 8; ++j) {
        const float re = role_embs[l * 64 + ro * 8 + j];
        ss += re * w[16 + j];
        sd += re * w[24 + j];
        sn += re * wn[j];
      }
#pragma unroll
      for (int co = 0; co < 3; ++co) {
        float cs = 0.f, cd = 0.f, cn = 0.f;
#pragma unroll
        for (int j = 0; j < 8; ++j) {
          const float ce = col_embs[l * 24 + co * 8 + j];
          cs += ce * w[32 + j];
          cd += ce * w[40 + j];
          cn += ce * wn[8 + j];
        }
        const int k = ro * 3 + co;
        TSp[ob + k] = (__bf16)(ss + cs);
        TDp[ob + k] = (__bf16)(sd + cd + bias);
        TNp[ob + k] = (__bf16)(sn + cn + nbias);
      }
    }
#pragma unroll
    for (int k = 24; k < 32; ++k) {
      TSp[ob + k] = (__bf16)0.f;
      TDp[ob + k] = (__bf16)0.f;
      TNp[ob + k] = (__bf16)0.f;
    }
  }
}

// ---------------------------------------------------------------------------
// Scan: cnt -> exclusive prefix (in place) + stable copy cnt2.
// ---------------------------------------------------------------------------
__global__ __launch_bounds__(1024) void scan_kernel(int* __restrict__ cnt,
                                                    int* __restrict__ cnt2) {
  __shared__ int wsum[16];
  __shared__ int carry;
  const int tid = threadIdx.x, lane = tid & 63, wid = tid >> 6;
  if (tid == 0) carry = 0;
  __syncthreads();
  for (int base = 0; base < NBINS; base += 4096) {
    const int idx = base + tid * 4;
    int4 v = make_int4(0, 0, 0, 0);
    if (idx < NBINS) v = *(const int4*)&cnt[idx];
    const int s1 = v.x + v.y, s2 = s1 + v.z, tot = s2 + v.w;
    int x = tot;
#pragma unroll
    for (int d = 1; d < 64; d <<= 1) {
      const int y = __shfl_up(x, d, 64);
      if (lane >= d) x += y;
    }
    if (lane == 63) wsum[wid] = x;
    __syncthreads();
    int wpref = 0;
#pragma unroll
    for (int w = 0; w < 16; ++w)
      if (w < wid) wpref += wsum[w];
    const int ex = carry + wpref + (x - tot);
    if (idx < NBINS) {
      int4 o;
      o.x = ex; o.y = ex + v.x; o.z = ex + s1; o.w = ex + s2;
      *(int4*)&cnt[idx] = o;
      *(int4*)&cnt2[idx] = o;
    }
    __syncthreads();
    if (tid == 0) {
      int s = 0;
#pragma unroll
      for (int w = 0; w < 16; ++w) s += wsum[w];
      carry += s;
    }
    __syncthreads();
  }
}

// ---------------------------------------------------------------------------
// scem: payload scatter (0..3124) + dstS run-fill (3125..3320) +
// embed h (3321..4102, bf16, coalesced store).
// ---------------------------------------------------------------------------
__global__ __launch_bounds__(256, 4) void scem_kernel(
    const int* __restrict__ srcI, const int* __restrict__ dstI,
    const int* __restrict__ erel, int* __restrict__ cnt,
    const int* __restrict__ cnt2,
    int* __restrict__ esr, int* __restrict__ dstS,
    const float* __restrict__ scalars, const int* __restrict__ ncol,
    const int* __restrict__ nrole,
    const float* __restrict__ colEmb, const float* __restrict__ roleEmb,
    const float* __restrict__ inw, const float* __restrict__ inb,
    __bf16* __restrict__ h)
{
  if (blockIdx.x < 3125) {
    const int e = blockIdx.x * 256 + threadIdx.x;
    if (e < NE) {
      const int pos = atomicAdd(&cnt[dstI[e]], 1);
      esr[pos] = srcI[e] | (erel[e] << 16);
    }
    return;
  }
  if (blockIdx.x < 3321) {
    const int n = (blockIdx.x - 3125) * 256 + threadIdx.x;
    if (n < NN) {
      const int st = cnt2[n], en = cnt2[n + 1];
      for (int p = st; p < en; ++p) dstS[p] = n;
    }
    return;
  }
  __shared__ __align__(16) char uni[33792];
  auto Ain = (__bf16 (*)[40])uni;    // [64][40] input features
  auto Hs  = (__bf16 (*)[264])uni;   // [64][264] h tile (aliased)

  const int tid  = threadIdx.x;
  const int lane = tid & 63;
  const int wave = tid >> 6;
  const int l15  = lane & 15;
  const int quad = lane >> 4;
  const int n0   = (blockIdx.x - 3321) * 64;
  const int colW = wave * 64;
  const int rowS = tid >> 5, colS = (tid & 31) * 8;

  {
    const int row = tid >> 2, q = tid & 3;
    const int n = n0 + row;
    __bf16* dp = &Ain[row][q * 8];
    if (n < NN) {
      if (q < 2) {
#pragma unroll
        for (int j = 0; j < 8; ++j) dp[j] = (__bf16)scalars[(size_t)n * 16 + q * 8 + j];
      } else if (q == 2) {
        const int c = ncol[n];
#pragma unroll
        for (int j = 0; j < 8; ++j) dp[j] = (__bf16)colEmb[c * 8 + j];
      } else {
        const int r = nrole[n];
#pragma unroll
        for (int j = 0; j < 8; ++j) dp[j] = (__bf16)roleEmb[r * 8 + j];
      }
    } else {
#pragma unroll
      for (int j = 0; j < 8; ++j) dp[j] = (__bf16)0.f;
    }
  }
  __syncthreads();

  f32x4 acc[4][4] = {};
  {
    bf16x8 bfr[4], afr[4];
#pragma unroll
    for (int nj = 0; nj < 4; ++nj) {
      const int col = colW + nj * 16 + l15;
#pragma unroll
      for (int j = 0; j < 8; ++j) bfr[nj][j] = (__bf16)inw[(quad * 8 + j) * 256 + col];
    }
#pragma unroll
    for (int mi = 0; mi < 4; ++mi)
      afr[mi] = *(const bf16x8*)&Ain[mi * 16 + l15][quad * 8];
#pragma unroll
    for (int mi = 0; mi < 4; ++mi)
#pragma unroll
      for (int nj = 0; nj < 4; ++nj)
        acc[mi][nj] = mfma16(afr[mi], bfr[nj], acc[mi][nj]);
  }
  float bi[4];
#pragma unroll
  for (int nj = 0; nj < 4; ++nj) bi[nj] = inb[colW + nj * 16 + l15];
  __syncthreads();   // Ain reads done before Hs (aliased) write

#pragma unroll
  for (int mi = 0; mi < 4; ++mi)
#pragma unroll
    for (int r = 0; r < 4; ++r) {
      const int row = mi * 16 + quad * 4 + r;
#pragma unroll
      for (int nj = 0; nj < 4; ++nj)
        Hs[row][colW + nj * 16 + l15] = (__bf16)(acc[mi][nj][r] + bi[nj]);
    }
  __syncthreads();
#pragma unroll
  for (int it = 0; it < 8; ++it) {
    const int row = it * 8 + rowS;
    const int n = n0 + row;
    if (n < NN)
      *(bf16x8*)(h + (size_t)n * H + colS) = *(const bf16x8*)&Hs[row][colS];
  }
}

// ---------------------------------------------------------------------------
// pre: P = h @ (Ws|Wd) + T[role,col] (one half per block). Output f16.
// ---------------------------------------------------------------------------
__global__ __launch_bounds__(256, 4) void pre_kernel(
    const __bf16* __restrict__ h, const int* __restrict__ nrole,
    const int* __restrict__ ncol, const __bf16* __restrict__ wsd,
    const __bf16* __restrict__ TSp, const __bf16* __restrict__ TDp,
    __half* __restrict__ PS, __half* __restrict__ PD)
{
  __shared__ __align__(16) char uni[64 * 296 * 2];
  __shared__ int sTi[64];
  auto Hs  = (__bf16 (*)[296])uni;     // bf16 view (h + onehot)
  auto HsH = (__half (*)[296])uni;     // f16 view (P staging)

  const int tid  = threadIdx.x;
  const int lane = tid & 63;
  const int wave = tid >> 6;
  const int l15  = lane & 15;
  const int quad = lane >> 4;
  const int ng   = blockIdx.x >> 1;
  const int hf   = blockIdx.x & 1;
  const int n0   = ng * 64;
  const int colW = wave * 64;
  const int rowS = tid >> 5, colS = (tid & 31) * 8;

  if (tid < 64) {
    const int n = n0 + tid;
    sTi[tid] = (n < NN) ? (nrole[n] * 3 + ncol[n]) : 0;
  }
#pragma unroll
  for (int it = 0; it < 8; ++it) {
    const int row = it * 8 + rowS;
    const int n = n0 + row;
    bf16x8 v = bzero8();
    if (n < NN) v = *(const bf16x8*)(h + (size_t)n * H + colS);
    *(bf16x8*)&Hs[row][colS] = v;
  }
  __syncthreads();
  {
    const int row = tid >> 2, q = tid & 3;
    const int ti = sTi[row];
    bf16x8 v;
#pragma unroll
    for (int j = 0; j < 8; ++j) v[j] = (__bf16)((q * 8 + j == ti) ? 1.f : 0.f);
    *(bf16x8*)&Hs[row][256 + q * 8] = v;
  }
  __syncthreads();

  f32x4 ap[4][4] = {};
#pragma unroll
  for (int c = 0; c < 9; ++c) {
    const __bf16* bp = (c < 8) ? wsd + ((size_t)c * 512 + hf * 256) * 32
                               : (hf ? TDp : TSp);
    bf16x8 bfr[4], afr[4];
#pragma unroll
    for (int nj = 0; nj < 4; ++nj)
      bfr[nj] = *(const bf16x8*)(bp + ((size_t)(colW + nj * 16 + l15)) * 32 + quad * 8);
#pragma unroll
    for (int mi = 0; mi < 4; ++mi)
      afr[mi] = *(const bf16x8*)&Hs[mi * 16 + l15][c * 32 + quad * 8];
#pragma unroll
    for (int mi = 0; mi < 4; ++mi)
#pragma unroll
      for (int nj = 0; nj < 4; ++nj)
        ap[mi][nj] = mfma16(afr[mi], bfr[nj], ap[mi][nj]);
  }
  __syncthreads();   // Hs reads done

#pragma unroll
  for (int mi = 0; mi < 4; ++mi)
#pragma unroll
    for (int r = 0; r < 4; ++r) {
      const int row = mi * 16 + quad * 4 + r;
#pragma unroll
      for (int nj = 0; nj < 4; ++nj)
        HsH[row][colW + nj * 16 + l15] = __float2half(ap[mi][nj][r]);
    }
  __syncthreads();
  __half* P = hf ? PD : PS;
#pragma unroll
  for (int it = 0; it < 8; ++it) {
    const int row = it * 8 + rowS;
    const int n = n0 + row;
    if (n < NN)
      *(uint4*)(P + (size_t)n * H + colS) = *(const uint4*)&HsH[row][colS];
  }
}

// ---------------------------------------------------------------------------
// Fused edge MLP + segmented scatter. Entire path in f16 (packed math),
// GEMM2 via f16 MFMA. agg/bnd stores stay bf16 (node reads bf16).
// ---------------------------------------------------------------------------
__global__ __launch_bounds__(256, 4) void edge_kernel(
    const __half* __restrict__ PS, const __half* __restrict__ PD,
    __bf16* __restrict__ agg, __bf16* __restrict__ bnd,
    const int* __restrict__ esr, const int* __restrict__ dstS,
    const __half* __restrict__ TRb,
    const __half* __restrict__ e2p, const float* __restrict__ e2b)
{
  __shared__ __align__(16) char uni[34816];
  __shared__ __half sTrel[8][256];
  __shared__ int sSrc[64], sDst[64], sRel[64];

  auto A2  = (__half (*)[264])uni;      // [64][264]  m1 (f16) row-major
  auto A2t = (__half (*)[68])uni;       // [256][68]  m2 (f16) col-major (aliased)

  const int tid  = threadIdx.x;
  const int lane = tid & 63;
  const int wave = tid >> 6;
  const int l15  = lane & 15;
  const int quad = lane >> 4;
  const int e0   = blockIdx.x * 64;
  const int colW = wave * 64;

  if (tid < 64) {
    const int u = esr[e0 + tid];
    sSrc[tid] = u & 0xffff;
    sRel[tid] = u >> 16;
    sDst[tid] = dstS[e0 + tid];
  }
  {
    const int r = tid >> 5, cs = (tid & 31) * 8;
    *(h8*)&sTrel[r][cs] = *(const h8*)(TRb + r * 256 + cs);
  }
  __syncthreads();

  // ---- m1: packed f16 ----
  {
    const int brow = tid >> 5;
    const int cs = (tid & 31) * 8;
#pragma unroll
    for (int it = 0; it < 8; ++it) {
      const int row = it * 8 + brow;
      const h8 a = *(const h8*)(PS + (size_t)sSrc[row] * H + cs);
      const h8 b = *(const h8*)(PD + (size_t)sDst[row] * H + cs);
      const h8 t = *(const h8*)&sTrel[sRel[row]][cs];
      h8 o;
#pragma unroll
      for (int p = 0; p < 4; ++p)
        o.h[p] = silu2(__hadd2(__hadd2(a.h[p], b.h[p]), t.h[p]));
      *(h8*)&A2[row][cs] = o;
    }
  }
  __syncthreads();

  // ---- GEMM2 (f16 MFMA) ----
  f32x4 acc2[4][4] = {};
#pragma unroll
  for (int c = 0; c < 8; ++c) {
    f16x8 bfr[4], afr[4];
#pragma unroll
    for (int nj = 0; nj < 4; ++nj)
      bfr[nj] = *(const f16x8*)(e2p + ((size_t)c * 256 + colW + nj * 16 + l15) * 32 + quad * 8);
#pragma unroll
    for (int mi = 0; mi < 4; ++mi)
      afr[mi] = *(const f16x8*)&A2[mi * 16 + l15][c * 32 + quad * 8];
#pragma unroll
    for (int mi = 0; mi < 4; ++mi)
#pragma unroll
      for (int nj = 0; nj < 4; ++nj)
        acc2[mi][nj] = mfma16h(afr[mi], bfr[nj], acc2[mi][nj]);
  }

  float b2[4];
#pragma unroll
  for (int nj = 0; nj < 4; ++nj) b2[nj] = e2b[colW + nj * 16 + l15];
  __syncthreads();   // A2 reads done before A2t (aliased) write

  // ---- m2: pack pairs -> packed silu -> A2t ----
#pragma unroll
  for (int mi = 0; mi < 4; ++mi)
#pragma unroll
    for (int nj = 0; nj < 4; ++nj) {
      const int col = colW + nj * 16 + l15;
      const __half2 p0 = silu2(__floats2half2_rn(acc2[mi][nj][0] + b2[nj],
                                                 acc2[mi][nj][1] + b2[nj]));
      const __half2 p1 = silu2(__floats2half2_rn(acc2[mi][nj][2] + b2[nj],
                                                 acc2[mi][nj][3] + b2[nj]));
      __half2* dp = (__half2*)&A2t[col][mi * 16 + quad * 4];
      dp[0] = p0; dp[1] = p1;
    }
  __syncthreads();

  // ---- segmented reduce: thread = column; all plain stores (bf16) ----
  {
    const int col = tid;
    const bool f = (lane > 0) && (sDst[lane] != sDst[lane - 1]);
    const unsigned long long mask = __ballot(f);
    h4 v[16];
#pragma unroll
    for (int j = 0; j < 16; ++j) v[j] = *(const h4*)&A2t[col][j * 4];
    __bf16* bnd0 = bnd + ((size_t)2 * blockIdx.x) * 256 + col;
    float sum = 0.f;
    int s0 = 0;
#pragma unroll
    for (int r = 0; r < 64; ++r) {
      sum += __half2float(v[r >> 2].e[r & 3]);
      if (r == 63 || ((mask >> (r + 1)) & 1ull)) {
        const bool isFirst = (s0 == 0), isLast = (r == 63);
        if (isFirst) {
          bnd0[0] = (__bf16)(isLast ? 0.f : sum);
          if (isLast) bnd0[256] = (__bf16)sum;
        } else if (isLast) {
          bnd0[256] = (__bf16)sum;
        } else {
          agg[(size_t)sDst[r] * H + col] = (__bf16)sum;
        }
        sum = 0.f;
        s0 = r + 1;
      }
    }
  }
}

// ---------------------------------------------------------------------------
// node core (unchanged, bf16): GEMM1 + onehot TNp -> silu -> GEMM2 ->
// residual restage -> LayerNorm -> h_new (mode 0) or out (mode 1).
// ---------------------------------------------------------------------------
__global__ __launch_bounds__(256, 4) void node_kernel(
    __bf16* __restrict__ h, const __bf16* __restrict__ agg,
    const __bf16* __restrict__ bnd, const int* __restrict__ cnt2,
    const int* __restrict__ nrole, const int* __restrict__ ncol,
    const __bf16* __restrict__ n1p, const __bf16* __restrict__ TNp,
    const __bf16* __restrict__ n2p, const float* __restrict__ n2b,
    const float* __restrict__ lng, const float* __restrict__ lnb,
    const int mode,
    const __bf16* __restrict__ outp, const float* __restrict__ outb,
    float* __restrict__ out)
{
  __shared__ __align__(16) char uni[33792];
  __shared__ float sSum[64][4], sSsq[64][4];
  __shared__ int sTi[64], sPcnt[64], sPidx[64][4];

  auto Abuf = (__bf16 (*)[72])uni;   // [64][72]   GEMM1 staging
  auto A2   = (__bf16 (*)[264])uni;  // [64][264]  GEMM1 out / old-h / h_new

  const int tid  = threadIdx.x;
  const int lane = tid & 63;
  const int wave = tid >> 6;
  const int l15  = lane & 15;
  const int quad = lane >> 4;
  const int n0   = blockIdx.x * 64;
  const int colW = wave * 64;
  const int rowS = tid >> 5, colS = (tid & 31) * 8;

  if (tid < 64) {
    const int n = n0 + tid;
    int st = 0, en = 0, ti = 0;
    if (n < NN) {
      st = cnt2[n];
      en = cnt2[n + 1];
      ti = nrole[n] * 3 + ncol[n];
    }
    sTi[tid] = ti;
    int pc = 0, pidx[4] = {0, 0, 0, 0};
    if (en > st) {
      const int bs = st >> 6, be = (en - 1) >> 6;
      if (bs == be && (st & 63) != 0 && (en & 63) != 0) {
        pc = -1;                       // strictly interior: read agg row
      } else {
        for (int b = bs; b <= be && pc < 4; ++b) {
          if (b > bs || (st & 63) == 0) pidx[pc++] = 2 * b;
          if ((b < be || (en & 63) == 0) && pc < 4) pidx[pc++] = 2 * b + 1;
        }
      }
    }
    sPcnt[tid] = pc;
#pragma unroll
    for (int j = 0; j < 4; ++j) sPidx[tid][j] = pidx[j];
  }
  __syncthreads();

  f32x4 acc[4][4] = {};
  for (int s = 0; s < 8; ++s) {
    if (s) __syncthreads();
    if (s < 4) {
#pragma unroll
      for (int it = 0; it < 2; ++it) {
        const int t = tid + it * 256;
        const int row = t >> 3, seg = t & 7;
        const int n = n0 + row;
        bf16x8 v = bzero8();
        if (n < NN) v = *(const bf16x8*)(h + (size_t)n * H + s * 64 + seg * 8);
        *(bf16x8*)&Abuf[row][seg * 8] = v;
      }
    } else {
#pragma unroll
      for (int it = 0; it < 2; ++it) {
        const int t = tid + it * 256;
        const int row = t >> 3, seg = t & 7;
        const int off = (s - 4) * 64 + seg * 8;
        const int pc = sPcnt[row];
        bf16x8 v = bzero8();
        if (pc == -1) {
          v = *(const bf16x8*)(agg + (size_t)(n0 + row) * H + off);
        } else if (pc > 0) {
          float a8[8] = {0.f, 0.f, 0.f, 0.f, 0.f, 0.f, 0.f, 0.f};
          for (int j = 0; j < pc; ++j) {
            const bf16x8 pv = *(const bf16x8*)(bnd + (size_t)sPidx[row][j] * 256 + off);
#pragma unroll
            for (int k = 0; k < 8; ++k) a8[k] += (float)pv[k];
          }
#pragma unroll
          for (int k = 0; k < 8; ++k) v[k] = (__bf16)a8[k];
        }
        *(bf16x8*)&Abuf[row][seg * 8] = v;
      }
    }
    __syncthreads();
#pragma unroll
    for (int cc = 0; cc < 2; ++cc) {
      const int c = 2 * s + cc;
      bf16x8 bfr[4], afr[4];
#pragma unroll
      for (int nj = 0; nj < 4; ++nj)
        bfr[nj] = *(const bf16x8*)(n1p + ((size_t)c * 256 + colW + nj * 16 + l15) * 32 + quad * 8);
#pragma unroll
      for (int mi = 0; mi < 4; ++mi)
        afr[mi] = *(const bf16x8*)&Abuf[mi * 16 + l15][cc * 32 + quad * 8];
#pragma unroll
      for (int mi = 0; mi < 4; ++mi)
#pragma unroll
        for (int nj = 0; nj < 4; ++nj)
          acc[mi][nj] = mfma16(afr[mi], bfr[nj], acc[mi][nj]);
    }
  }
  // onehot stage -> chunk 16 (TNp table add, includes n1b)
  __syncthreads();
  {
    const int row = tid >> 2, q = tid & 3;
    const int ti = sTi[row];
    bf16x8 v;
#pragma unroll
    for (int j = 0; j < 8; ++j) v[j] = (__bf16)((q * 8 + j == ti) ? 1.f : 0.f);
    *(bf16x8*)&Abuf[row][q * 8] = v;
  }
  __syncthreads();
  {
    bf16x8 bfr[4], afr[4];
#pragma unroll
    for (int nj = 0; nj < 4; ++nj)
      bfr[nj] = *(const bf16x8*)(TNp + ((size_t)(colW + nj * 16 + l15)) * 32 + quad * 8);
#pragma unroll
    for (int mi = 0; mi < 4; ++mi)
      afr[mi] = *(const bf16x8*)&Abuf[mi * 16 + l15][quad * 8];
#pragma unroll
    for (int mi = 0; mi < 4; ++mi)
#pragma unroll
      for (int nj = 0; nj < 4; ++nj)
        acc[mi][nj] = mfma16(afr[mi], bfr[nj], acc[mi][nj]);
  }
  __syncthreads();   // Abuf reads done before A2 (aliased) write

  // GEMM1 epilogue: silu -> A2
#pragma unroll
  for (int mi = 0; mi < 4; ++mi)
#pragma unroll
    for (int r = 0; r < 4; ++r) {
      const int row = mi * 16 + quad * 4 + r;
#pragma unroll
      for (int nj = 0; nj < 4; ++nj)
        A2[row][colW + nj * 16 + l15] = (__bf16)silu_f(acc[mi][nj][r]);
    }
  __syncthreads();

  f32x4 acc2[4][4] = {};
#pragma unroll
  for (int c = 0; c < 8; ++c) {
    bf16x8 bfr[4], afr[4];
#pragma unroll
    for (int nj = 0; nj < 4; ++nj)
      bfr[nj] = *(const bf16x8*)(n2p + ((size_t)c * 256 + colW + nj * 16 + l15) * 32 + quad * 8);
#pragma unroll
    for (int mi = 0; mi < 4; ++mi)
      afr[mi] = *(const bf16x8*)&A2[mi * 16 + l15][c * 32 + quad * 8];
#pragma unroll
    for (int mi = 0; mi < 4; ++mi)
#pragma unroll
      for (int nj = 0; nj < 4; ++nj)
        acc2[mi][nj] = mfma16(afr[mi], bfr[nj], acc2[mi][nj]);
  }
  __syncthreads();   // A2 (silu vals) reads done

  // restage old h into A2 for the residual
#pragma unroll
  for (int it = 0; it < 8; ++it) {
    const int row = it * 8 + rowS;
    const int n = n0 + row;
    bf16x8 v = bzero8();
    if (n < NN) v = *(const bf16x8*)(h + (size_t)n * H + colS);
    *(bf16x8*)&A2[row][colS] = v;
  }
  __syncthreads();

  float b2[4], g4[4], bb4[4];
#pragma unroll
  for (int nj = 0; nj < 4; ++nj) {
    const int col = colW + nj * 16 + l15;
    b2[nj] = n2b[col]; g4[nj] = lng[col]; bb4[nj] = lnb[col];
  }
#pragma unroll
  for (int mi = 0; mi < 4; ++mi)
#pragma unroll
    for (int nj = 0; nj < 4; ++nj) {
      const int col = colW + nj * 16 + l15;
#pragma unroll
      for (int r = 0; r < 4; ++r)
        acc2[mi][nj][r] += b2[nj] + (float)A2[mi * 16 + quad * 4 + r][col];
    }

#pragma unroll
  for (int mi = 0; mi < 4; ++mi)
#pragma unroll
    for (int r = 0; r < 4; ++r) {
      float s1 = 0.f, s2 = 0.f;
#pragma unroll
      for (int nj = 0; nj < 4; ++nj) {
        const float v = acc2[mi][nj][r];
        s1 += v; s2 += v * v;
      }
#pragma unroll
      for (int d = 1; d < 16; d <<= 1) {
        s1 += __shfl_xor(s1, d, 16);
        s2 += __shfl_xor(s2, d, 16);
      }
      if (l15 == 0) {
        const int row = mi * 16 + quad * 4 + r;
        sSum[row][wave] = s1; sSsq[row][wave] = s2;
      }
    }
  __syncthreads();   // all residual reads of A2 complete; stats visible

#pragma unroll
  for (int mi = 0; mi < 4; ++mi)
#pragma unroll
    for (int r = 0; r < 4; ++r) {
      const int row = mi * 16 + quad * 4 + r;
      const float t1 = sSum[row][0] + sSum[row][1] + sSum[row][2] + sSum[row][3];
      const float t2 = sSsq[row][0] + sSsq[row][1] + sSsq[row][2] + sSsq[row][3];
      const float mu = t1 * (1.f / 256.f);
      float var = t2 * (1.f / 256.f) - mu * mu;
      var = var < 0.f ? 0.f : var;
      const float rstd = rsqrtf(var + 1e-5f);
#pragma unroll
      for (int nj = 0; nj < 4; ++nj) {
        const int col = colW + nj * 16 + l15;
        const float o = g4[nj] * (acc2[mi][nj][r] - mu) * rstd + bb4[nj];
        A2[row][col] = (__bf16)o;
      }
    }
  __syncthreads();   // h_new staged in A2

  if (mode == 0) {
#pragma unroll
    for (int it = 0; it < 8; ++it) {
      const int row = it * 8 + rowS;
      const int n = n0 + row;
      if (n < NN)
        *(bf16x8*)(h + (size_t)n * H + colS) = *(const bf16x8*)&A2[row][colS];
    }
  } else {
    f32x4 ao[4] = {};
#pragma unroll
    for (int c = 0; c < 8; ++c) {
      const bf16x8 bfr = *(const bf16x8*)(outp + ((size_t)c * 64 + wave * 16 + l15) * 32 + quad * 8);
#pragma unroll
      for (int mi = 0; mi < 4; ++mi) {
        const bf16x8 afr = *(const bf16x8*)&A2[mi * 16 + l15][c * 32 + quad * 8];
        ao[mi] = mfma16(afr, bfr, ao[mi]);
      }
    }
    const float ob = outb[wave * 16 + l15];
#pragma unroll
    for (int mi = 0; mi < 4; ++mi)
#pragma unroll
      for (int r = 0; r < 4; ++r) {
        const int n = n0 + mi * 16 + quad * 4 + r;
        if (n < NN) out[(size_t)n * 64 + wave * 16 + l15] = ao[mi][r] + ob;
      }
  }
}

// ---------------------------------------------------------------------------
extern "C" void kernel_launch(void* const* d_in, const int* in_sizes, int n_in,
                              void* d_out, int out_size, void* d_ws, size_t ws_size,
                              hipStream_t stream) {
  const float* scalars   = (const float*)d_in[0];
  const int*   ei        = (const int*)d_in[1];
  const int*   erel      = (const int*)d_in[2];
  const int*   ncol      = (const int*)d_in[3];
  const int*   nrole     = (const int*)d_in[4];
  const float* blk_role  = (const float*)d_in[5];
  const float* blk_col   = (const float*)d_in[6];
  const float* inw       = (const float*)d_in[7];
  const float* inb       = (const float*)d_in[8];
  const float* rel_embs  = (const float*)d_in[9];
  const float* role_embs = (const float*)d_in[10];
  const float* col_embs  = (const float*)d_in[11];
  const float* e1w       = (const float*)d_in[12];
  const float* e1b       = (const float*)d_in[13];
  const float* e2w       = (const float*)d_in[14];
  const float* e2b       = (const float*)d_in[15];
  const float* n1w       = (const float*)d_in[16];
  const float* n1b       = (const float*)d_in[17];
  const float* n2w       = (const float*)d_in[18];
  const float* n2b       = (const float*)d_in[19];
  const float* lng       = (const float*)d_in[20];
  const float* lnb       = (const float*)d_in[21];
  const float* outw      = (const float*)d_in[22];
  const float* outb      = (const float*)d_in[23];

  const int* srcI = ei;
  const int* dstI = ei + NE;

  char* ws = (char*)d_ws;
  size_t off = 0;
  auto take = [&](size_t bytes) -> char* {
    off = (off + 255) & ~(size_t)255;
    char* p = ws + off;
    off += bytes;
    return p;
  };
  __bf16* h    = (__bf16*)take((size_t)NN * H * 2);
  __bf16* agg  = (__bf16*)take((size_t)NN * H * 2);
  __bf16* bnd  = (__bf16*)take((size_t)2 * NB * 256 * 2);
  __half* PS   = (__half*)take((size_t)NN * H * 2);
  __half* PD   = (__half*)take((size_t)NN * H * 2);
  __bf16* wsd  = (__bf16*)take((size_t)3 * 131072 * 2);
  __half* e2p  = (__half*)take((size_t)3 * 65536 * 2);
  __bf16* n1p  = (__bf16*)take((size_t)3 * 131072 * 2);
  __bf16* n2p  = (__bf16*)take((size_t)3 * 65536 * 2);
  __bf16* outp = (__bf16*)take((size_t)16384 * 2);
  __half* TRb  = (__half*)take((size_t)3 * 8 * 256 * 2);
  __bf16* TNp  = (__bf16*)take((size_t)3 * 8192 * 2);
  __bf16* TSp  = (__bf16*)take((size_t)3 * 8192 * 2);
  __bf16* TDp  = (__bf16*)take((size_t)3 * 8192 * 2);
  int*    cnt  = (int*)take((size_t)NBINS * 4);
  int*    cnt2 = (int*)take((size_t)NBINS * 4);
  int*    esr  = (int*)take((size_t)NE * 4);
  int*    dstS = (int*)take((size_t)NE * 4);

  hipMemsetAsync(cnt, 0, (size_t)NBINS * 4, stream);
  preph_kernel<<<7800, 256, 0, stream>>>(
      e1w, e2w, n1w, n2w, outw, e1b, n1b, rel_embs, role_embs, col_embs, dstI,
      wsd, e2p, n1p, n2p, outp, cnt, TRb, TNp, TSp, TDp);
  scan_kernel<<<1, 1024, 0, stream>>>(cnt, cnt2);
  scem_kernel<<<4103, 256, 0, stream>>>(
      srcI, dstI, erel, cnt, cnt2, esr, dstS,
      scalars, ncol, nrole, blk_col, blk_role, inw, inb, h);
  pre_kernel<<<2 * HBLK, 256, 0, stream>>>(
      h, nrole, ncol, wsd, TSp, TDp, PS, PD);

  for (int l = 0; l < 3; ++l) {
    edge_kernel<<<NB, 256, 0, stream>>>(
        PS, PD, agg, bnd, esr, dstS, TRb + (size_t)l * 2048,
        e2p + (size_t)l * 65536, e2b + (size_t)l * 256);
    const int mode = (l < 2) ? 0 : 1;
    node_kernel<<<HBLK, 256, 0, stream>>>(
        h, agg, bnd, cnt2, nrole, ncol,
        n1p + (size_t)l * 131072, TNp + (size_t)l * 8192,
        n2p + (size_t)l * 65536,  n2b + (size_t)l * 256,
        lng + (size_t)l * 256, lnb + (size_t)l * 256,
        mode, outp, outb, (float*)d_out);
    if (l < 2) {
      const int ln = l + 1;
      pre_kernel<<<2 * HBLK, 256, 0, stream>>>(
          h, nrole, ncol, wsd + (size_t)ln * 131072,
          TSp + (size_t)ln * 8192, TDp + (size_t)ln * 8192, PS, PD);
    }
  }
}